// Round 24
// baseline (703.712 us; speedup 1.0000x reference)
//
#include <hip/hip_runtime.h>
#include <hip/hip_bf16.h>

#define NU 100000
#define NT 300000
#define NM 10000

typedef __hip_bfloat16 bf16;
typedef __attribute__((ext_vector_type(8))) short bf16x8;
typedef __attribute__((ext_vector_type(4))) float f32x4;

__device__ __forceinline__ float toF(float v) { return v; }
__device__ __forceinline__ float toF(bf16 v)  { return __bfloat162float(v); }
__device__ __forceinline__ float bitsLo(unsigned u) { return __uint_as_float(u << 16); }
__device__ __forceinline__ float bitsHi(unsigned u) { return __uint_as_float(u & 0xffff0000u); }
__device__ __forceinline__ float shortBF(short s) { return __uint_as_float(((unsigned)(unsigned short)s) << 16); }
__device__ __forceinline__ short bfBits(float v) { bf16 b = __float2bfloat16(v); return *(short*)&b; }
__device__ __forceinline__ uint2 pack4bf(float a0, float a1, float a2, float a3) {
    bf16 b0 = __float2bfloat16(a0), b1 = __float2bfloat16(a1);
    bf16 b2 = __float2bfloat16(a2), b3 = __float2bfloat16(a3);
    uint2 r;
    r.x = ((unsigned)(*(unsigned short*)&b1) << 16) | (unsigned)(*(unsigned short*)&b0);
    r.y = ((unsigned)(*(unsigned short*)&b3) << 16) | (unsigned)(*(unsigned short*)&b2);
    return r;
}

struct Segs {
    const int* ei[7];
    int eoff[8];
    int n3off[8];
    int nboff[8];
    int slot[8];
};

struct P3 {
    const bf16* wt[3];
    const float4* waS[3];
    bf16* hs[3];
    float* aS[3];
    const float4* wadL; float* aDL;   // nullable
    const float4* wadA; float* aDA;
    const float4* wadB; float* aDB;
};

struct PJ { const float* x; const bf16* wt; const float* bias; bf16* out; int N; };
struct PMX { const bf16* x; P3 p; int N; };
struct FGA {
    const int* rp; const unsigned* degp; const int* col;
    const float *aS0, *aS1, *aS2;
    const float *aD0, *aD1, *aD2;
    const bf16 *h0, *h1, *h2;
    const float* cb; int b0, b1, b2; bf16* out; int Nd;
};

// ================= device bodies =================
__device__ __forceinline__ void hist_body(const Segs& s, int TE, int* __restrict__ cnt3,
                                          int* __restrict__ rank, int bid) {
    int g = bid * 256 + threadIdx.x;
    if (g >= TE) return;
    int r = 0;
    while (g >= s.eoff[r + 1]) r++;
    int e = g - s.eoff[r];
    int E = s.eoff[r + 1] - s.eoff[r];
    int d = s.ei[r][E + e];
    rank[g] = atomicAdd(&cnt3[s.n3off[r] + d], 1);
}

__device__ __forceinline__ void fill_body(const Segs& s, int TE, const int* __restrict__ rp_all,
                                          const unsigned* __restrict__ degp,
                                          const int* __restrict__ rank, int* __restrict__ col,
                                          int bid) {
    int g = bid * 256 + threadIdx.x;
    if (g >= TE) return;
    int r = 0;
    while (g >= s.eoff[r + 1]) r++;
    int e = g - s.eoff[r];
    int E = s.eoff[r + 1] - s.eoff[r];
    int d = s.ei[r][E + e];
    int ni = s.nboff[r] + d;
    unsigned dp = degp[ni];
    int sl = s.slot[r];
    int segoff = (sl == 0) ? 0 : ((sl == 1) ? (int)(dp & 1023)
                                            : (int)((dp & 1023) + ((dp >> 10) & 1023)));
    col[rp_all[ni] + segoff + rank[g]] = s.ei[r][e];
}

// MFMA operand-swapped projection: D row=channel, col=node -> packed 8B stores
template <int K>
__device__ __forceinline__ void projm_body(const float* __restrict__ x, const bf16* __restrict__ wt,
                                           const float* __restrict__ bias, bf16* __restrict__ out,
                                           int N, int bid) {
    constexpr int KP = (K > 32) ? 64 : 32;
    int w = threadIdx.x >> 6, lane = threadIdx.x & 63;
    int m = lane & 15, kq = lane >> 4;
    int r0 = bid * 64 + w * 16;
    int row = r0 + m;
    bf16x8 ah0 = {}, al0 = {}, ah1 = {}, al1 = {};
    if (row < N) {
#pragma unroll
        for (int j = 0; j < 8; j++) {
            int k = kq * 8 + j;
            float v = (k < K) ? x[(size_t)row * K + k] : 0.f;
            short hb = bfBits(v);
            ah0[j] = hb;
            al0[j] = bfBits(v - shortBF(hb));
        }
        if (KP == 64) {
#pragma unroll
            for (int j = 0; j < 8; j++) {
                float v = x[(size_t)row * K + 32 + kq * 8 + j];
                short hb = bfBits(v);
                ah1[j] = hb;
                al1[j] = bfBits(v - shortBF(hb));
            }
        }
    }
#pragma unroll
    for (int nt = 0; nt < 4; nt++) {
        int c = nt * 16 + m;
        f32x4 acc = {};
        const bf16* bh = wt + c * KP + kq * 8;
        const bf16* bl = wt + 64 * KP + c * KP + kq * 8;
        bf16x8 bh0 = *(const bf16x8*)(bh);
        bf16x8 bl0 = *(const bf16x8*)(bl);
        acc = __builtin_amdgcn_mfma_f32_16x16x32_bf16(bh0, ah0, acc, 0, 0, 0);
        acc = __builtin_amdgcn_mfma_f32_16x16x32_bf16(bh0, al0, acc, 0, 0, 0);
        acc = __builtin_amdgcn_mfma_f32_16x16x32_bf16(bl0, ah0, acc, 0, 0, 0);
        if (KP == 64) {
            bf16x8 bh1 = *(const bf16x8*)(bh + 32);
            bf16x8 bl1 = *(const bf16x8*)(bl + 32);
            acc = __builtin_amdgcn_mfma_f32_16x16x32_bf16(bh1, ah1, acc, 0, 0, 0);
            acc = __builtin_amdgcn_mfma_f32_16x16x32_bf16(bh1, al1, acc, 0, 0, 0);
            acc = __builtin_amdgcn_mfma_f32_16x16x32_bf16(bl1, ah1, acc, 0, 0, 0);
        }
        // D: row = channel nt*16 + kq*4 + i, col = node r0+m
        if (row < N) {
            float4 bv = *(const float4*)(bias + nt * 16 + kq * 4);
            uint2 pk = pack4bf(acc[0] + bv.x, acc[1] + bv.y, acc[2] + bv.z, acc[3] + bv.w);
            *(uint2*)(out + (size_t)row * 64 + nt * 16 + kq * 4) = pk;
        }
    }
}

__device__ __forceinline__ void alpha_gemv(const float4* __restrict__ w4,
                                           const float* __restrict__ xv,
                                           int kq, int row, int N,
                                           float* __restrict__ out) {
    float p0 = 0.f, p1 = 0.f, p2 = 0.f, p3 = 0.f;
#pragma unroll
    for (int kk = 0; kk < 8; kk++) {
        float4 wA = w4[kq * 8 + kk];
        p0 = fmaf(xv[kk], wA.x, p0); p1 = fmaf(xv[kk], wA.y, p1);
        p2 = fmaf(xv[kk], wA.z, p2); p3 = fmaf(xv[kk], wA.w, p3);
        float4 wB = w4[32 + kq * 8 + kk];
        p0 = fmaf(xv[8 + kk], wB.x, p0); p1 = fmaf(xv[8 + kk], wB.y, p1);
        p2 = fmaf(xv[8 + kk], wB.z, p2); p3 = fmaf(xv[8 + kk], wB.w, p3);
    }
    p0 += __shfl_xor(p0, 16); p0 += __shfl_xor(p0, 32);
    p1 += __shfl_xor(p1, 16); p1 += __shfl_xor(p1, 32);
    p2 += __shfl_xor(p2, 16); p2 += __shfl_xor(p2, 32);
    p3 += __shfl_xor(p3, 16); p3 += __shfl_xor(p3, 32);
    if (kq == 0 && row < N) {
        float4 o; o.x = p0; o.y = p1; o.z = p2; o.w = p3;
        *(float4*)(out + (size_t)row * 4) = o;
    }
}

template <int NREL>
__device__ __forceinline__ void pm3_body(const bf16* __restrict__ x, const P3& p, int N,
                                         bf16* swt, int bid) {
    int tid = threadIdx.x;
    int w = tid >> 6, lane = tid & 63;
    int m = lane & 15, kq = lane >> 4;
    int r0 = bid * 64 + w * 16;
    bf16x8 a0 = {}, a1 = {};
    int row = r0 + m;
    if (row < N) {
        a0 = *(const bf16x8*)(x + (size_t)row * 64 + kq * 8);
        a1 = *(const bf16x8*)(x + (size_t)row * 64 + 32 + kq * 8);
    }
    auto ldw = [&](int r, int b) -> bf16x8 {
        int sb = b ^ ((r & 7) << 4);
        return *(const bf16x8*)((const char*)swt + r * 128 + sb);
    };
#pragma unroll
    for (int rl = 0; rl < NREL; rl++) {
        __syncthreads();
        {
            const uint4* src = (const uint4*)p.wt[rl];
            for (int i = tid; i < 1024; i += 256) {
                int r = i >> 3, b = (i & 7) << 4;
                int sb = b ^ ((r & 7) << 4);
                *(uint4*)((char*)swt + r * 128 + sb) = src[i];
            }
        }
        __syncthreads();
        bf16* hs = p.hs[rl];
#pragma unroll
        for (int nt = 0; nt < 4; nt++) {
            int rw = nt * 16 + m;
            bf16x8 bh0 = ldw(rw, kq * 16);
            bf16x8 bh1 = ldw(rw, kq * 16 + 64);
            bf16x8 bl0 = ldw(64 + rw, kq * 16);
            bf16x8 bl1 = ldw(64 + rw, kq * 16 + 64);
            f32x4 acc = {};
            acc = __builtin_amdgcn_mfma_f32_16x16x32_bf16(bh0, a0, acc, 0, 0, 0);
            acc = __builtin_amdgcn_mfma_f32_16x16x32_bf16(bl0, a0, acc, 0, 0, 0);
            acc = __builtin_amdgcn_mfma_f32_16x16x32_bf16(bh1, a1, acc, 0, 0, 0);
            acc = __builtin_amdgcn_mfma_f32_16x16x32_bf16(bl1, a1, acc, 0, 0, 0);
            // D: row = channel nt*16 + kq*4 + i, col = node r0+m
            if (row < N) {
                uint2 pk = pack4bf(acc[0], acc[1], acc[2], acc[3]);
                *(uint2*)(hs + (size_t)row * 64 + nt * 16 + kq * 4) = pk;
            }
        }
    }
    float xv[16];
#pragma unroll
    for (int kk = 0; kk < 8; kk++) { xv[kk] = shortBF(a0[kk]); xv[8 + kk] = shortBF(a1[kk]); }
#pragma unroll
    for (int rl = 0; rl < NREL; rl++)
        alpha_gemv(p.waS[rl], xv, kq, row, N, p.aS[rl]);
    if (p.wadL) alpha_gemv(p.wadL, xv, kq, row, N, p.aDL);
    if (p.wadA) alpha_gemv(p.wadA, xv, kq, row, N, p.aDA);
    if (p.wadB) alpha_gemv(p.wadB, xv, kq, row, N, p.aDB);
}

template <int EPR>
__device__ __forceinline__ void seg_agg(const int* __restrict__ col, int s, int d,
                                        const float* __restrict__ aS, float adv,
                                        const bf16* __restrict__ hp,
                                        int l32, int hcl, float& ox, float& oy) {
    float dn = 0.f, ax = 0.f, ay = 0.f;
    for (int i0 = 0; i0 < d; i0 += EPR) {
        int mrem = d - i0;
        int cw[EPR];
#pragma unroll
        for (int j = 0; j < EPR; j++) cw[j] = (j < mrem) ? col[s + i0 + j] : 0;
        float as[EPR];
#pragma unroll
        for (int j = 0; j < EPR; j++) as[j] = (j < mrem) ? aS[cw[j] * 4 + hcl] : 0.f;
        unsigned hv[EPR];
#pragma unroll
        for (int j = 0; j < EPR; j++)
            hv[j] = (j < mrem) ? *(const unsigned*)(hp + (size_t)cw[j] * 64 + 2 * l32) : 0u;
#pragma unroll
        for (int j = 0; j < EPR; j++) if (j < mrem) {
            float a = as[j] + adv;
            a = (a >= 0.f) ? a : 0.2f * a;
            float ex = __expf(a);
            dn += ex;
            ax = fmaf(ex, bitsLo(hv[j]), ax);
            ay = fmaf(ex, bitsHi(hv[j]), ay);
        }
    }
    float rd = 1.f / (dn + 1e-16f);
    ox = fmaf(ax, rd, ox);
    oy = fmaf(ay, rd, oy);
}

template <int NREL, int EPR>
__device__ __forceinline__ void fagg3_body(const FGA& a, int bid) {
    int tid = threadIdx.x;
    int wv = tid >> 6, lane = tid & 63;
    int half = lane >> 5, l32 = lane & 31;
    int node = bid * 8 + wv * 2 + half;
    bool alive = node < a.Nd;
    int nc = alive ? node : (a.Nd - 1);
    int hcl = l32 >> 3;
    int s = a.rp[nc];
    unsigned dp = a.degp[nc];
    int d0 = dp & 1023, d1 = (dp >> 10) & 1023, d2 = (dp >> 20) & 1023;
    float2 bb = *(const float2*)(a.cb + a.b0 * 64 + 2 * l32);
    float ox = bb.x, oy = bb.y;
    if (a.b1 >= 0) { float2 t = *(const float2*)(a.cb + a.b1 * 64 + 2 * l32); ox += t.x; oy += t.y; }
    if (a.b2 >= 0) { float2 t = *(const float2*)(a.cb + a.b2 * 64 + 2 * l32); ox += t.x; oy += t.y; }
    seg_agg<EPR>(a.col, s, d0, a.aS0, a.aD0[nc * 4 + hcl], a.h0, l32, hcl, ox, oy);
    seg_agg<EPR>(a.col, s + d0, d1, a.aS1, a.aD1[nc * 4 + hcl], a.h1, l32, hcl, ox, oy);
    if (NREL > 2)
        seg_agg<EPR>(a.col, s + d0 + d1, d2, a.aS2, a.aD2[nc * 4 + hcl], a.h2, l32, hcl, ox, oy);
    ox = ox > 0.f ? ox : 0.f;
    oy = oy > 0.f ? oy : 0.f;
    if (alive) {
        bf16 p0 = __float2bfloat16(ox), p1 = __float2bfloat16(oy);
        unsigned pk = ((unsigned)(*(unsigned short*)&p1) << 16) | (unsigned)(*(unsigned short*)&p0);
        ((unsigned*)a.out)[(size_t)node * 32 + l32] = pk;
    }
}

// ================= fused kernels =================
__global__ void k_fuseA(Segs s, int TE, int* cnt3, int* rank,
                        PJ pt, PJ pu, PJ pm, int Hb, int T, int Pt, int Pu) {
    int bid = blockIdx.x;
    int hA  = (int)(((long long)bid * Hb) / T);
    int hA1 = (int)(((long long)(bid + 1) * Hb) / T);
    if (hA1 > hA) {
        hist_body(s, TE, cnt3, rank, hA);
    } else {
        int pidx = bid - hA;
        if (pidx < Pt)            projm_body<64>(pt.x, pt.wt, pt.bias, pt.out, pt.N, pidx);
        else if (pidx < Pt + Pu)  projm_body<32>(pu.x, pu.wt, pu.bias, pu.out, pu.N, pidx - Pt);
        else                      projm_body<16>(pm.x, pm.wt, pm.bias, pm.out, pm.N, pidx - Pt - Pu);
    }
}

// layer-0 fused: CSR fill || triple projection (Bresenham)
__global__ __launch_bounds__(256, 8) void k_pmf3xF(PMX a, PMX b, PMX c, int e0, int e1,
                                                   Segs s, int TE, const int* rp_all,
                                                   const unsigned* degp, const int* rank,
                                                   int* col, int Fb, int T) {
    __shared__ bf16 swt[8192];
    int bid = blockIdx.x;
    int fA  = (int)(((long long)bid * Fb) / T);
    int fA1 = (int)(((long long)(bid + 1) * Fb) / T);
    if (fA1 > fA) {
        fill_body(s, TE, rp_all, degp, rank, col, fA);
    } else {
        int pidx = bid - fA;
        if (pidx < e0)      pm3_body<3>(a.x, a.p, a.N, swt, pidx);
        else if (pidx < e1) pm3_body<2>(b.x, b.p, b.N, swt, pidx - e0);
        else                pm3_body<2>(c.x, c.p, c.N, swt, pidx - e1);
    }
}

// plain fused triple projection (layer-0 fallback)
__global__ __launch_bounds__(256, 8) void k_pmf3x(PMX a, PMX b, PMX c, int e0, int e1) {
    __shared__ bf16 swt[8192];
    int bid = blockIdx.x;
    if (bid < e0)      pm3_body<3>(a.x, a.p, a.N, swt, bid);
    else if (bid < e1) pm3_body<2>(b.x, b.p, b.N, swt, bid - e0);
    else               pm3_body<2>(c.x, c.p, c.N, swt, bid - e1);
}

// fuseB: L0 u/m aggregation || L1 t-src projection (independent, complementary pipes)
__global__ __launch_bounds__(256, 8) void k_fuseB(FGA u, FGA mm, int e0, PMX pt, int Fb, int T) {
    __shared__ bf16 swt[8192];
    int bid = blockIdx.x;
    int fA  = (int)(((long long)bid * Fb) / T);
    int fA1 = (int)(((long long)(bid + 1) * Fb) / T);
    if (fA1 > fA) {
        if (fA < e0) fagg3_body<2, 8>(u, fA);
        else         fagg3_body<2, 8>(mm, fA - e0);
    } else {
        pm3_body<1>(pt.x, pt.p, pt.N, swt, bid - fA);
    }
}

// two single-relation projections (L1 u-src, m-src)
__global__ __launch_bounds__(256, 8) void k_pmf1s(PMX a, PMX b, int e0) {
    __shared__ bf16 swt[8192];
    int bid = blockIdx.x;
    if (bid < e0) pm3_body<1>(a.x, a.p, a.N, swt, bid);
    else          pm3_body<1>(b.x, b.p, b.N, swt, bid - e0);
}

// single 3-relation aggregation (L0 t-group / L1 t-group)
__global__ void k_fagg1(FGA a) {
    fagg3_body<3, 4>(a, blockIdx.x);
}

__global__ void k_fill_all(Segs s, int TE, const int* __restrict__ rp_all,
                           const unsigned* __restrict__ degp,
                           const int* __restrict__ rank, int* __restrict__ col) {
    fill_body(s, TE, rp_all, degp, rank, col, blockIdx.x);
}

// ================= small kernels =================
__global__ void k_zero_i(int* __restrict__ p, int n) {
    int i = blockIdx.x * 256 + threadIdx.x;
    if (i < n) p[i] = 0;
}

__global__ void k_mkrp(const int* __restrict__ cnt3, int* __restrict__ cnt,
                       unsigned* __restrict__ degp) {
    int i = blockIdx.x * 256 + threadIdx.x;
    int TN = NU + NT + NM;
    if (i >= TN) return;
    int b3, N, n, nrel;
    if (i < NU)            { b3 = 3 * NT;            N = NU; n = i;            nrel = 2; }
    else if (i < NU + NT)  { b3 = 0;                 N = NT; n = i - NU;       nrel = 3; }
    else                   { b3 = 3 * NT + 2 * NU;   N = NM; n = i - NU - NT;  nrel = 2; }
    int d0 = cnt3[b3 + n];
    int d1 = cnt3[b3 + N + n];
    int d2 = (nrel == 3) ? cnt3[b3 + 2 * N + n] : 0;
    cnt[i] = d0 + d1 + d2;
    degp[i] = (unsigned)d0 | ((unsigned)d1 << 10) | ((unsigned)d2 << 20);
}

__global__ void k_scan1(const int* __restrict__ cnt, int n, int* __restrict__ bsum) {
    __shared__ int sh[256];
    int i = blockIdx.x * 256 + threadIdx.x;
    sh[threadIdx.x] = (i < n) ? cnt[i] : 0;
    __syncthreads();
    for (int o = 128; o; o >>= 1) {
        if (threadIdx.x < o) sh[threadIdx.x] += sh[threadIdx.x + o];
        __syncthreads();
    }
    if (threadIdx.x == 0) bsum[blockIdx.x] = sh[0];
}

__global__ void k_scan2(int* __restrict__ bsum, int nb) {  // 1 block
    __shared__ int sh[256];
    __shared__ int carry;
    if (threadIdx.x == 0) carry = 0;
    __syncthreads();
    for (int base = 0; base < nb; base += 256) {
        int i = base + threadIdx.x;
        int v = (i < nb) ? bsum[i] : 0;
        sh[threadIdx.x] = v;
        __syncthreads();
        for (int o = 1; o < 256; o <<= 1) {
            int t = (threadIdx.x >= o) ? sh[threadIdx.x - o] : 0;
            __syncthreads();
            sh[threadIdx.x] += t;
            __syncthreads();
        }
        if (i < nb) bsum[i] = carry + sh[threadIdx.x] - v;  // exclusive
        __syncthreads();
        if (threadIdx.x == 255) carry += sh[255];
        __syncthreads();
    }
}

__global__ void k_scan3(const int* __restrict__ cnt, int n, const int* __restrict__ bsum,
                        int* __restrict__ out) {
    __shared__ int sh[256];
    int i = blockIdx.x * 256 + threadIdx.x;
    int v = (i < n) ? cnt[i] : 0;
    sh[threadIdx.x] = v;
    __syncthreads();
    for (int o = 1; o < 256; o <<= 1) {
        int t = (threadIdx.x >= o) ? sh[threadIdx.x - o] : 0;
        __syncthreads();
        sh[threadIdx.x] += t;
        __syncthreads();
    }
    if (i <= n) out[i] = bsum[blockIdx.x] + sh[threadIdx.x] - v;
}

__global__ void k_wa(const float* __restrict__ lin_w, const float* __restrict__ att_s,
                     const float* __restrict__ att_d, float* __restrict__ was,
                     float* __restrict__ wad) {
    int i = blockIdx.x * 256 + threadIdx.x;
    if (i >= 2 * 7 * 64 * 8) return;
    int j = i & 7;
    int k = (i >> 3) & 63;
    int lr = i >> 9;
    int h = j & 3;
    const float* a = (j < 4 ? att_s : att_d) + lr * 64 + h * 16;
    const float* Wp = lin_w + (size_t)lr * 4096 + k * 64 + h * 16;
    float s = 0.f;
#pragma unroll
    for (int c = 0; c < 16; c++) s += Wp[c] * a[c];
    if (j < 4) was[lr * 256 + k * 4 + h] = s;
    else       wad[lr * 256 + k * 4 + h] = s;
}

__global__ void k_wt(const float* __restrict__ lin_w, bf16* __restrict__ wt) {
    int i = blockIdx.x * 256 + threadIdx.x;
    if (i >= 14 * 4096) return;
    int lr = i >> 12;
    int kc = i & 4095;
    int k = kc >> 6, c = kc & 63;
    float v = lin_w[(size_t)lr * 4096 + k * 64 + c];
    bf16 hi = __float2bfloat16(v);
    float rem = v - __bfloat162float(hi);
    wt[(size_t)lr * 8192 + c * 64 + k] = hi;
    wt[(size_t)lr * 8192 + 4096 + c * 64 + k] = __float2bfloat16(rem);
}

__global__ void k_wtin(const float* __restrict__ Wu, const float* __restrict__ Wt,
                       const float* __restrict__ Wm, bf16* __restrict__ out) {
    int i = blockIdx.x * 256 + threadIdx.x;
    if (i >= 8192) return;
    const float* W; int K, KP, base, j;
    if (i < 2048)      { W = Wu; K = 32; KP = 32; base = 0;     j = i; }
    else if (i < 6144) { W = Wt; K = 64; KP = 64; base = 4096;  j = i - 2048; }
    else               { W = Wm; K = 16; KP = 32; base = 12288; j = i - 6144; }
    int c = j / KP, k = j - c * KP;
    float v = (k < K) ? W[k * 64 + c] : 0.f;
    bf16 hb = __float2bfloat16(v);
    float rem = v - __bfloat162float(hb);
    out[base + c * KP + k] = hb;
    out[base + 64 * KP + c * KP + k] = __float2bfloat16(rem);
}

// ================= classifier =================
__global__ void k_cls(const bf16* __restrict__ t, const float* __restrict__ w1,
                      const float* __restrict__ b1, const float* __restrict__ w2,
                      const float* __restrict__ b2, float* __restrict__ out) {
    __shared__ float w1s[64 * 32];
    __shared__ float w2s[64];
    __shared__ float b1s[32];
    __shared__ float b2s[2];
    __shared__ float ts[8 * 64];
    int tid = threadIdx.x;
    for (int i = tid; i < 2048; i += 256) w1s[i] = w1[i];
    if (tid < 64) w2s[tid] = w2[tid];
    if (tid < 32) b1s[tid] = b1[tid];
    if (tid < 2) b2s[tid] = b2[tid];
    int n0 = blockIdx.x << 3;
    for (int i = tid; i < 512; i += 256) {
        int row = i >> 6, col = i & 63;
        ts[i] = toF(t[(size_t)(n0 + row) * 64 + col]);
    }
    __syncthreads();
    int lane = tid & 31;
    int row = tid >> 5;
    float h = b1s[lane];
#pragma unroll 8
    for (int k = 0; k < 64; k++) h = fmaf(ts[(row << 6) + k], w1s[(k << 5) + lane], h);
    h = h > 0.f ? h : 0.f;
    float o0 = h * w2s[lane * 2 + 0];
    float o1 = h * w2s[lane * 2 + 1];
#pragma unroll
    for (int off = 16; off; off >>= 1) {
        o0 += __shfl_down(o0, off, 32);
        o1 += __shfl_down(o1, off, 32);
    }
    if (lane == 0) {
        int n = n0 + row;
        out[(size_t)n * 2 + 0] = o0 + b2s[0];
        out[(size_t)n * 2 + 1] = o1 + b2s[1];
    }
}

extern "C" void kernel_launch(void* const* d_in, const int* in_sizes, int n_in,
                              void* d_out, int out_size, void* d_ws, size_t ws_size,
                              hipStream_t stream) {
    (void)n_in; (void)out_size;
    const float* x_user  = (const float*)d_in[0];
    const float* x_tx    = (const float*)d_in[1];
    const float* x_merch = (const float*)d_in[2];
    const int* ei[7];
    int E[7];
    for (int r = 0; r < 7; r++) { ei[r] = (const int*)d_in[3 + r]; E[r] = in_sizes[3 + r] / 2; }
    const float* Win_user  = (const float*)d_in[10];
    const float* bin_user  = (const float*)d_in[11];
    const float* Win_tx    = (const float*)d_in[12];
    const float* bin_tx    = (const float*)d_in[13];
    const float* Win_merch = (const float*)d_in[14];
    const float* bin_merch = (const float*)d_in[15];
    const float* lin_w     = (const float*)d_in[16];
    const float* att_src   = (const float*)d_in[17];
    const float* att_dst   = (const float*)d_in[18];
    const float* conv_bias = (const float*)d_in[19];
    const float* cls_w1    = (const float*)d_in[20];
    const float* cls_b1    = (const float*)d_in[21];
    const float* cls_w2    = (const float*)d_in[22];
    const float* cls_b2    = (const float*)d_in[23];

    const int src_type[7] = {0, 1, 2, 1, 0, 2, 1};
    const int dst_type[7] = {1, 0, 1, 2, 0, 2, 1};
    const int N_of[3] = {NU, NT, NM};
    const int type_base[3] = {0, NU, NU + NT};
    const int type3_base[3] = {3 * NT, 0, 3 * NT + 2 * NU};
    const int rel_slot[7] = {0, 0, 1, 0, 1, 1, 2};

    Segs segs;
    int TE = 0;
    int TN = NU + NT + NM;
    int TN3 = 3 * NT + 2 * NU + 2 * NM;
    for (int r = 0; r < 7; r++) {
        segs.ei[r] = ei[r];
        segs.eoff[r] = TE; TE += E[r];
        int dt = dst_type[r];
        segs.n3off[r] = type3_base[dt] + rel_slot[r] * N_of[dt];
        segs.nboff[r] = type_base[dt];
        segs.slot[r] = rel_slot[r];
    }
    segs.eoff[7] = TE;

    // ---- adaptive workspace layout ----
    bf16* A[3]; bf16* hsArr[7];
    float* aS7[7]; float* aD7[7];
    int *rp_all, *col_all, *cnt3, *cnt, *rank, *bsum;
    unsigned* degp;
    float *was, *wad; bf16 *wt, *wtin;
    char* base = (char*)d_ws;
    size_t off;
    auto alloc = [&](size_t bytes) { size_t q = off; off += (bytes + 255) & ~(size_t)255; return q; };
    size_t hs_first;

    auto layout = [&](bool rankReal) -> bool {
        off = 0;
        for (int t = 0; t < 3; t++) A[t] = (bf16*)(base + alloc((size_t)N_of[t] * 128));
        hs_first = (size_t)-1;
        for (int r = 0; r < 7; r++) {
            size_t o = alloc((size_t)N_of[src_type[r]] * 128);
            if (hs_first == (size_t)-1) hs_first = o;
            hsArr[r] = (bf16*)(base + o);
        }
        for (int r = 0; r < 7; r++) aS7[r] = (float*)(base + alloc((size_t)N_of[src_type[r]] * 16));
        for (int r = 0; r < 7; r++) aD7[r] = (float*)(base + alloc((size_t)N_of[dst_type[r]] * 16));
        rp_all  = (int*)(base + alloc(((size_t)TN + 1) * 4));
        degp    = (unsigned*)(base + alloc((size_t)TN * 4));
        col_all = (int*)(base + alloc((size_t)TE * 4));
        bsum    = (int*)(base + alloc((size_t)8192 * 4));
        was     = (float*)(base + alloc((size_t)14 * 256 * 4));
        wad     = (float*)(base + alloc((size_t)14 * 256 * 4));
        wt      = (bf16*)(base + alloc((size_t)14 * 8192 * 2));
        wtin    = (bf16*)(base + alloc((size_t)16384 * 2));
        if (rankReal) rank = (int*)(base + alloc((size_t)TE * 4));
        size_t o_cnt3 = hs_first;
        size_t o_cnt  = o_cnt3 + (((size_t)TN3 * 4 + 255) & ~(size_t)255);
        cnt3 = (int*)(base + o_cnt3);
        cnt  = (int*)(base + o_cnt);
        if (!rankReal) {
            size_t o_rank = o_cnt + (((size_t)TN * 4 + 255) & ~(size_t)255);
            rank = (int*)(base + o_rank);
        }
        return off <= ws_size;
    };
    bool fuseFill = layout(true);
    if (!fuseFill && !layout(false)) return;  // scratch too small: fail cleanly

    // ---- prep ----
    k_wa<<<(7168 + 255) / 256, 256, 0, stream>>>(lin_w, att_src, att_dst, was, wad);
    k_wt<<<(14 * 4096 + 255) / 256, 256, 0, stream>>>(lin_w, wt);
    k_wtin<<<32, 256, 0, stream>>>(Win_user, Win_tx, Win_merch, wtin);
    k_zero_i<<<(TN3 + 255) / 256, 256, 0, stream>>>(cnt3, TN3);

    // ---- fuseA: hist || input projections (Bresenham) ----
    int Hb = (TE + 255) / 256;
    int Pt = (NT + 63) / 64, Pu = (NU + 63) / 64, Pm = (NM + 63) / 64;
    {
        PJ pt = {x_tx, wtin + 4096, bin_tx, A[1], NT};
        PJ pu = {x_user, wtin, bin_user, A[0], NU};
        PJ pm = {x_merch, wtin + 12288, bin_merch, A[2], NM};
        int T = Hb + Pt + Pu + Pm;
        k_fuseA<<<T, 256, 0, stream>>>(segs, TE, cnt3, rank, pt, pu, pm, Hb, T, Pt, Pu);
    }

    // ---- CSR mid chain ----
    int nb = (TN + 256) / 256;
    k_mkrp<<<(TN + 255) / 256, 256, 0, stream>>>(cnt3, cnt, degp);
    k_scan1<<<nb, 256, 0, stream>>>(cnt, TN, bsum);
    k_scan2<<<1, 256, 0, stream>>>(bsum, nb);
    k_scan3<<<nb, 256, 0, stream>>>(cnt, TN, bsum, rp_all);
    if (!fuseFill)
        k_fill_all<<<(TE + 255) / 256, 256, 0, stream>>>(segs, TE, rp_all, degp, rank, col_all);

    const int bat_src[3]     = {1, 0, 2};
    const int bat_rels[3][3] = {{1, 3, 6}, {0, 4, -1}, {2, 5, -1}};
    const int bat_wad[3][2]  = {{0, 2}, {1, -1}, {3, -1}};

    // ================= layer 0 projections (all 7 relations) =================
    {
        int l = 0;
        PMX pmx[3];
        for (int b = 0; b < 3; b++) {
            int st = bat_src[b];
            int nrel = (bat_rels[b][2] >= 0) ? 3 : 2;
            P3 p;
            for (int jj = 0; jj < 3; jj++) {
                int r = bat_rels[b][jj] >= 0 ? bat_rels[b][jj] : bat_rels[b][0];
                int lr = l * 7 + r;
                p.wt[jj]  = wt + (size_t)lr * 8192;
                p.waS[jj] = (const float4*)(was + (size_t)lr * 256);
                p.hs[jj]  = hsArr[r];
                p.aS[jj]  = aS7[r];
            }
            int selfR = bat_rels[b][nrel - 1];
            p.wadL = (const float4*)(wad + (size_t)(l * 7 + selfR) * 256);
            p.aDL  = aD7[selfR];
            int wr0 = bat_wad[b][0], wr1 = bat_wad[b][1];
            p.wadA = (const float4*)(wad + (size_t)(l * 7 + wr0) * 256);
            p.aDA  = aD7[wr0];
            p.wadB = (wr1 >= 0) ? (const float4*)(wad + (size_t)(l * 7 + wr1) * 256) : nullptr;
            p.aDB  = (wr1 >= 0) ? aD7[wr1] : nullptr;
            pmx[b].x = A[st];
            pmx[b].p = p;
            pmx[b].N = N_of[st];
        }
        int b0 = (pmx[0].N + 63) / 64;
        int b1 = (pmx[1].N + 63) / 64;
        int b2 = (pmx[2].N + 63) / 64;
        if (fuseFill) {
            int Fb = (TE + 255) / 256;
            int T = Fb + b0 + b1 + b2;
            k_pmf3xF<<<T, 256, 0, stream>>>(pmx[0], pmx[1], pmx[2], b0, b0 + b1,
                                            segs, TE, rp_all, degp, rank, col_all, Fb, T);
        } else {
            k_pmf3x<<<b0 + b1 + b2, 256, 0, stream>>>(pmx[0], pmx[1], pmx[2], b0, b0 + b1);
        }
    }

    // ================= L0 t-group aggregation =================
    FGA fgt0;
    {
        fgt0.rp   = rp_all + type_base[1];
        fgt0.degp = degp + type_base[1];
        fgt0.col  = col_all;
        fgt0.aS0 = aS7[0]; fgt0.aS1 = aS7[2]; fgt0.aS2 = aS7[6];
        fgt0.aD0 = aD7[0]; fgt0.aD1 = aD7[2]; fgt0.aD2 = aD7[6];
        fgt0.h0 = hsArr[0]; fgt0.h1 = hsArr[2]; fgt0.h2 = hsArr[6];
        fgt0.cb = conv_bias; fgt0.b0 = 0; fgt0.b1 = 2; fgt0.b2 = 6;
        fgt0.out = A[1]; fgt0.Nd = NT;
        k_fagg1<<<(NT + 7) / 8, 256, 0, stream>>>(fgt0);
    }

    // ================= fuseB: L0 u/m aggregation || L1 t-src projection =================
    {
        FGA fu, fm;
        fu.rp   = rp_all + type_base[0];
        fu.degp = degp + type_base[0];
        fu.col  = col_all;
        fu.aS0 = aS7[1]; fu.aS1 = aS7[4]; fu.aS2 = aS7[1];
        fu.aD0 = aD7[1]; fu.aD1 = aD7[4]; fu.aD2 = aD7[1];
        fu.h0 = hsArr[1]; fu.h1 = hsArr[4]; fu.h2 = hsArr[1];
        fu.cb = conv_bias; fu.b0 = 1; fu.b1 = 4; fu.b2 = -1;
        fu.out = A[0]; fu.Nd = NU;
        fm.rp   = rp_all + type_base[2];
        fm.degp = degp + type_base[2];
        fm.col  = col_all;
        fm.aS0 = aS7[3]; fm.aS1 = aS7[5]; fm.aS2 = aS7[3];
        fm.aD0 = aD7[3]; fm.aD1 = aD7[5]; fm.aD2 = aD7[3];
        fm.h0 = hsArr[3]; fm.h1 = hsArr[5]; fm.h2 = hsArr[3];
        fm.cb = conv_bias; fm.b0 = 3; fm.b1 = 5; fm.b2 = -1;
        fm.out = A[2]; fm.Nd = NM;

        PMX pt;
        {
            P3 p = {};
            int lr = 7 + 6;
            p.wt[0]  = wt + (size_t)lr * 8192;
            p.waS[0] = (const float4*)(was + (size_t)lr * 256);
            p.hs[0]  = hsArr[6];
            p.aS[0]  = aS7[6];
            p.wadL = (const float4*)(wad + (size_t)lr * 256);
            p.aDL  = aD7[6];
            p.wadA = (const float4*)(wad + (size_t)(7 + 0) * 256);
            p.aDA  = aD7[0];
            p.wadB = (const float4*)(wad + (size_t)(7 + 2) * 256);
            p.aDB  = aD7[2];
            pt.x = A[1]; pt.p = p; pt.N = NT;
        }
        int ub = (NU + 7) / 8;
        int mb = (NM + 7) / 8;
        int Fb = ub + mb;
        int Pb = (NT + 63) / 64;
        int T = Fb + Pb;
        k_fuseB<<<T, 256, 0, stream>>>(fu, fm, ub, pt, Fb, T);
    }

    // ================= L1 u-src, m-src projections =================
    {
        PMX pu, pm;
        {
            P3 p = {};
            int lr = 7 + 0;
            p.wt[0]  = wt + (size_t)lr * 8192;
            p.waS[0] = (const float4*)(was + (size_t)lr * 256);
            p.hs[0]  = hsArr[0];
            p.aS[0]  = aS7[0];
            pu.x = A[0]; pu.p = p; pu.N = NU;
        }
        {
            P3 p = {};
            int lr = 7 + 2;
            p.wt[0]  = wt + (size_t)lr * 8192;
            p.waS[0] = (const float4*)(was + (size_t)lr * 256);
            p.hs[0]  = hsArr[2];
            p.aS[0]  = aS7[2];
            pm.x = A[2]; pm.p = p; pm.N = NM;
        }
        int b0 = (NU + 63) / 64;
        int b1 = (NM + 63) / 64;
        k_pmf1s<<<b0 + b1, 256, 0, stream>>>(pu, pm, b0);
    }

    // ================= L1 t-group aggregation =================
    {
        FGA a;
        a.rp   = rp_all + type_base[1];
        a.degp = degp + type_base[1];
        a.col  = col_all;
        a.aS0 = aS7[0]; a.aS1 = aS7[2]; a.aS2 = aS7[6];
        a.aD0 = aD7[0]; a.aD1 = aD7[2]; a.aD2 = aD7[6];
        a.h0 = hsArr[0]; a.h1 = hsArr[2]; a.h2 = hsArr[6];
        a.cb = conv_bias + (size_t)7 * 64; a.b0 = 0; a.b1 = 2; a.b2 = 6;
        a.out = A[1]; a.Nd = NT;
        k_fagg1<<<(NT + 7) / 8, 256, 0, stream>>>(a);
    }
    k_cls<<<NT / 8, 256, 0, stream>>>(A[1], cls_w1, cls_b1, cls_w2, cls_b2, (float*)d_out);
}

// Round 25
// 674.403 us; speedup vs baseline: 1.0435x; 1.0435x over previous
//
#include <hip/hip_runtime.h>
#include <hip/hip_bf16.h>

#define NU 100000
#define NT 300000
#define NM 10000

typedef __hip_bfloat16 bf16;
typedef __attribute__((ext_vector_type(8))) short bf16x8;
typedef __attribute__((ext_vector_type(4))) float f32x4;

__device__ __forceinline__ float toF(float v) { return v; }
__device__ __forceinline__ float toF(bf16 v)  { return __bfloat162float(v); }
__device__ __forceinline__ float bitsLo(unsigned u) { return __uint_as_float(u << 16); }
__device__ __forceinline__ float bitsHi(unsigned u) { return __uint_as_float(u & 0xffff0000u); }
__device__ __forceinline__ float shortBF(short s) { return __uint_as_float(((unsigned)(unsigned short)s) << 16); }
__device__ __forceinline__ short bfBits(float v) { bf16 b = __float2bfloat16(v); return *(short*)&b; }

struct Segs {
    const int* ei[7];
    int eoff[8];
    int n3off[8];
    int nboff[8];
    int slot[8];
};

struct P3 {
    const bf16* wt[3];
    const float4* waS[3];
    bf16* hs[3];
    float* aS[3];
    const float4* wadL; float* aDL;   // nullable
    const float4* wadA; float* aDA;
    const float4* wadB; float* aDB;
};

struct PJ { const float* x; const bf16* wt; const float* bias; bf16* out; int N; };
struct PMX { const bf16* x; P3 p; int N; };
struct FGA {
    const int* rp; const unsigned* degp; const int* col;
    const float *aS0, *aS1, *aS2;
    const float *aD0, *aD1, *aD2;
    const bf16 *h0, *h1, *h2;
    const float* cb; int b0, b1, b2; bf16* out; int Nd;
};

// ================= device bodies =================
__device__ __forceinline__ void hist_body(const Segs& s, int TE, int* __restrict__ cnt3,
                                          int* __restrict__ rank, int bid) {
    int g = bid * 256 + threadIdx.x;
    if (g >= TE) return;
    int r = 0;
    while (g >= s.eoff[r + 1]) r++;
    int e = g - s.eoff[r];
    int E = s.eoff[r + 1] - s.eoff[r];
    int d = s.ei[r][E + e];
    rank[g] = atomicAdd(&cnt3[s.n3off[r] + d], 1);
}

__device__ __forceinline__ void fill_body(const Segs& s, int TE, const int* __restrict__ rp_all,
                                          const unsigned* __restrict__ degp,
                                          const int* __restrict__ rank, int* __restrict__ col,
                                          int bid) {
    int g = bid * 256 + threadIdx.x;
    if (g >= TE) return;
    int r = 0;
    while (g >= s.eoff[r + 1]) r++;
    int e = g - s.eoff[r];
    int E = s.eoff[r + 1] - s.eoff[r];
    int d = s.ei[r][E + e];
    int ni = s.nboff[r] + d;
    unsigned dp = degp[ni];
    int sl = s.slot[r];
    int segoff = (sl == 0) ? 0 : ((sl == 1) ? (int)(dp & 1023)
                                            : (int)((dp & 1023) + ((dp >> 10) & 1023)));
    col[rp_all[ni] + segoff + rank[g]] = s.ei[r][e];
}

template <int K>
__device__ __forceinline__ void projm_body(const float* __restrict__ x, const bf16* __restrict__ wt,
                                           const float* __restrict__ bias, bf16* __restrict__ out,
                                           int N, int bid) {
    constexpr int KP = (K > 32) ? 64 : 32;
    int w = threadIdx.x >> 6, lane = threadIdx.x & 63;
    int m = lane & 15, kq = lane >> 4;
    int r0 = bid * 64 + w * 16;
    int row = r0 + m;
    bf16x8 ah0 = {}, al0 = {}, ah1 = {}, al1 = {};
    if (row < N) {
#pragma unroll
        for (int j = 0; j < 8; j++) {
            int k = kq * 8 + j;
            float v = (k < K) ? x[(size_t)row * K + k] : 0.f;
            short hb = bfBits(v);
            ah0[j] = hb;
            al0[j] = bfBits(v - shortBF(hb));
        }
        if (KP == 64) {
#pragma unroll
            for (int j = 0; j < 8; j++) {
                float v = x[(size_t)row * K + 32 + kq * 8 + j];
                short hb = bfBits(v);
                ah1[j] = hb;
                al1[j] = bfBits(v - shortBF(hb));
            }
        }
    }
#pragma unroll
    for (int nt = 0; nt < 4; nt++) {
        int c = nt * 16 + m;
        f32x4 acc = {};
        const bf16* bh = wt + c * KP + kq * 8;
        const bf16* bl = wt + 64 * KP + c * KP + kq * 8;
        bf16x8 bh0 = *(const bf16x8*)(bh);
        bf16x8 bl0 = *(const bf16x8*)(bl);
        acc = __builtin_amdgcn_mfma_f32_16x16x32_bf16(ah0, bh0, acc, 0, 0, 0);
        acc = __builtin_amdgcn_mfma_f32_16x16x32_bf16(al0, bh0, acc, 0, 0, 0);
        acc = __builtin_amdgcn_mfma_f32_16x16x32_bf16(ah0, bl0, acc, 0, 0, 0);
        if (KP == 64) {
            bf16x8 bh1 = *(const bf16x8*)(bh + 32);
            bf16x8 bl1 = *(const bf16x8*)(bl + 32);
            acc = __builtin_amdgcn_mfma_f32_16x16x32_bf16(ah1, bh1, acc, 0, 0, 0);
            acc = __builtin_amdgcn_mfma_f32_16x16x32_bf16(al1, bh1, acc, 0, 0, 0);
            acc = __builtin_amdgcn_mfma_f32_16x16x32_bf16(ah1, bl1, acc, 0, 0, 0);
        }
        float bv = bias[c];
#pragma unroll
        for (int i = 0; i < 4; i++) {
            int rr = r0 + kq * 4 + i;
            if (rr < N) out[(size_t)rr * 64 + c] = __float2bfloat16(acc[i] + bv);
        }
    }
}

__device__ __forceinline__ void alpha_gemv(const float4* __restrict__ w4,
                                           const float* __restrict__ xv,
                                           int kq, int row, int N,
                                           float* __restrict__ out) {
    float p0 = 0.f, p1 = 0.f, p2 = 0.f, p3 = 0.f;
#pragma unroll
    for (int kk = 0; kk < 8; kk++) {
        float4 wA = w4[kq * 8 + kk];
        p0 = fmaf(xv[kk], wA.x, p0); p1 = fmaf(xv[kk], wA.y, p1);
        p2 = fmaf(xv[kk], wA.z, p2); p3 = fmaf(xv[kk], wA.w, p3);
        float4 wB = w4[32 + kq * 8 + kk];
        p0 = fmaf(xv[8 + kk], wB.x, p0); p1 = fmaf(xv[8 + kk], wB.y, p1);
        p2 = fmaf(xv[8 + kk], wB.z, p2); p3 = fmaf(xv[8 + kk], wB.w, p3);
    }
    p0 += __shfl_xor(p0, 16); p0 += __shfl_xor(p0, 32);
    p1 += __shfl_xor(p1, 16); p1 += __shfl_xor(p1, 32);
    p2 += __shfl_xor(p2, 16); p2 += __shfl_xor(p2, 32);
    p3 += __shfl_xor(p3, 16); p3 += __shfl_xor(p3, 32);
    if (kq == 0 && row < N) {
        float4 o; o.x = p0; o.y = p1; o.z = p2; o.w = p3;
        *(float4*)(out + (size_t)row * 4) = o;
    }
}

template <int NREL>
__device__ __forceinline__ void pm3_body(const bf16* __restrict__ x, const P3& p, int N,
                                         bf16* swt, int bid) {
    int tid = threadIdx.x;
    int w = tid >> 6, lane = tid & 63;
    int m = lane & 15, kq = lane >> 4;
    int r0 = bid * 64 + w * 16;
    bf16x8 a0 = {}, a1 = {};
    int row = r0 + m;
    if (row < N) {
        a0 = *(const bf16x8*)(x + (size_t)row * 64 + kq * 8);
        a1 = *(const bf16x8*)(x + (size_t)row * 64 + 32 + kq * 8);
    }
    auto ldw = [&](int r, int b) -> bf16x8 {
        int sb = b ^ ((r & 7) << 4);
        return *(const bf16x8*)((const char*)swt + r * 128 + sb);
    };
#pragma unroll
    for (int rl = 0; rl < NREL; rl++) {
        __syncthreads();
        {
            const uint4* src = (const uint4*)p.wt[rl];
            for (int i = tid; i < 1024; i += 256) {
                int r = i >> 3, b = (i & 7) << 4;
                int sb = b ^ ((r & 7) << 4);
                *(uint4*)((char*)swt + r * 128 + sb) = src[i];
            }
        }
        __syncthreads();
        bf16* hs = p.hs[rl];
#pragma unroll
        for (int nt = 0; nt < 4; nt++) {
            int rw = nt * 16 + m;
            bf16x8 bh0 = ldw(rw, kq * 16);
            bf16x8 bh1 = ldw(rw, kq * 16 + 64);
            bf16x8 bl0 = ldw(64 + rw, kq * 16);
            bf16x8 bl1 = ldw(64 + rw, kq * 16 + 64);
            f32x4 acc = {};
            acc = __builtin_amdgcn_mfma_f32_16x16x32_bf16(a0, bh0, acc, 0, 0, 0);
            acc = __builtin_amdgcn_mfma_f32_16x16x32_bf16(a0, bl0, acc, 0, 0, 0);
            acc = __builtin_amdgcn_mfma_f32_16x16x32_bf16(a1, bh1, acc, 0, 0, 0);
            acc = __builtin_amdgcn_mfma_f32_16x16x32_bf16(a1, bl1, acc, 0, 0, 0);
#pragma unroll
            for (int i = 0; i < 4; i++) {
                int rr = r0 + kq * 4 + i;
                if (rr < N) hs[(size_t)rr * 64 + nt * 16 + m] = __float2bfloat16(acc[i]);
            }
        }
    }
    float xv[16];
#pragma unroll
    for (int kk = 0; kk < 8; kk++) { xv[kk] = shortBF(a0[kk]); xv[8 + kk] = shortBF(a1[kk]); }
#pragma unroll
    for (int rl = 0; rl < NREL; rl++)
        alpha_gemv(p.waS[rl], xv, kq, row, N, p.aS[rl]);
    if (p.wadL) alpha_gemv(p.wadL, xv, kq, row, N, p.aDL);
    if (p.wadA) alpha_gemv(p.wadA, xv, kq, row, N, p.aDA);
    if (p.wadB) alpha_gemv(p.wadB, xv, kq, row, N, p.aDB);
}

template <int EPR>
__device__ __forceinline__ void seg_agg(const int* __restrict__ col, int s, int d,
                                        const float* __restrict__ aS, float adv,
                                        const bf16* __restrict__ hp,
                                        int l32, int hcl, float& ox, float& oy) {
    float dn = 0.f, ax = 0.f, ay = 0.f;
    for (int i0 = 0; i0 < d; i0 += EPR) {
        int mrem = d - i0;
        int cw[EPR];
#pragma unroll
        for (int j = 0; j < EPR; j++) cw[j] = (j < mrem) ? col[s + i0 + j] : 0;
        float as[EPR];
#pragma unroll
        for (int j = 0; j < EPR; j++) as[j] = (j < mrem) ? aS[cw[j] * 4 + hcl] : 0.f;
        unsigned hv[EPR];
#pragma unroll
        for (int j = 0; j < EPR; j++)
            hv[j] = (j < mrem) ? *(const unsigned*)(hp + (size_t)cw[j] * 64 + 2 * l32) : 0u;
#pragma unroll
        for (int j = 0; j < EPR; j++) if (j < mrem) {
            float a = as[j] + adv;
            a = (a >= 0.f) ? a : 0.2f * a;
            float ex = __expf(a);
            dn += ex;
            ax = fmaf(ex, bitsLo(hv[j]), ax);
            ay = fmaf(ex, bitsHi(hv[j]), ay);
        }
    }
    float rd = 1.f / (dn + 1e-16f);
    ox = fmaf(ax, rd, ox);
    oy = fmaf(ay, rd, oy);
}

template <int NREL, int EPR>
__device__ __forceinline__ void fagg3_body(const FGA& a, int bid) {
    int tid = threadIdx.x;
    int wv = tid >> 6, lane = tid & 63;
    int half = lane >> 5, l32 = lane & 31;
    int node = bid * 8 + wv * 2 + half;
    bool alive = node < a.Nd;
    int nc = alive ? node : (a.Nd - 1);
    int hcl = l32 >> 3;
    int s = a.rp[nc];
    unsigned dp = a.degp[nc];
    int d0 = dp & 1023, d1 = (dp >> 10) & 1023, d2 = (dp >> 20) & 1023;
    float2 bb = *(const float2*)(a.cb + a.b0 * 64 + 2 * l32);
    float ox = bb.x, oy = bb.y;
    if (a.b1 >= 0) { float2 t = *(const float2*)(a.cb + a.b1 * 64 + 2 * l32); ox += t.x; oy += t.y; }
    if (a.b2 >= 0) { float2 t = *(const float2*)(a.cb + a.b2 * 64 + 2 * l32); ox += t.x; oy += t.y; }
    seg_agg<EPR>(a.col, s, d0, a.aS0, a.aD0[nc * 4 + hcl], a.h0, l32, hcl, ox, oy);
    seg_agg<EPR>(a.col, s + d0, d1, a.aS1, a.aD1[nc * 4 + hcl], a.h1, l32, hcl, ox, oy);
    if (NREL > 2)
        seg_agg<EPR>(a.col, s + d0 + d1, d2, a.aS2, a.aD2[nc * 4 + hcl], a.h2, l32, hcl, ox, oy);
    ox = ox > 0.f ? ox : 0.f;
    oy = oy > 0.f ? oy : 0.f;
    if (alive) {
        bf16 p0 = __float2bfloat16(ox), p1 = __float2bfloat16(oy);
        unsigned pk = ((unsigned)(*(unsigned short*)&p1) << 16) | (unsigned)(*(unsigned short*)&p0);
        ((unsigned*)a.out)[(size_t)node * 32 + l32] = pk;
    }
}

// ================= fused kernels =================
__global__ void k_fuseA(Segs s, int TE, int* cnt3, int* rank,
                        PJ pt, PJ pu, PJ pm, int Hb, int T, int Pt, int Pu) {
    int bid = blockIdx.x;
    int hA  = (int)(((long long)bid * Hb) / T);
    int hA1 = (int)(((long long)(bid + 1) * Hb) / T);
    if (hA1 > hA) {
        hist_body(s, TE, cnt3, rank, hA);
    } else {
        int pidx = bid - hA;
        if (pidx < Pt)            projm_body<64>(pt.x, pt.wt, pt.bias, pt.out, pt.N, pidx);
        else if (pidx < Pt + Pu)  projm_body<32>(pu.x, pu.wt, pu.bias, pu.out, pu.N, pidx - Pt);
        else                      projm_body<16>(pm.x, pm.wt, pm.bias, pm.out, pm.N, pidx - Pt - Pu);
    }
}

// layer-0 fused: CSR fill || triple projection (Bresenham)
__global__ __launch_bounds__(256, 8) void k_pmf3xF(PMX a, PMX b, PMX c, int e0, int e1,
                                                   Segs s, int TE, const int* rp_all,
                                                   const unsigned* degp, const int* rank,
                                                   int* col, int Fb, int T) {
    __shared__ bf16 swt[8192];
    int bid = blockIdx.x;
    int fA  = (int)(((long long)bid * Fb) / T);
    int fA1 = (int)(((long long)(bid + 1) * Fb) / T);
    if (fA1 > fA) {
        fill_body(s, TE, rp_all, degp, rank, col, fA);
    } else {
        int pidx = bid - fA;
        if (pidx < e0)      pm3_body<3>(a.x, a.p, a.N, swt, pidx);
        else if (pidx < e1) pm3_body<2>(b.x, b.p, b.N, swt, pidx - e0);
        else                pm3_body<2>(c.x, c.p, c.N, swt, pidx - e1);
    }
}

// plain fused triple projection (layer-0 fallback)
__global__ __launch_bounds__(256, 8) void k_pmf3x(PMX a, PMX b, PMX c, int e0, int e1) {
    __shared__ bf16 swt[8192];
    int bid = blockIdx.x;
    if (bid < e0)      pm3_body<3>(a.x, a.p, a.N, swt, bid);
    else if (bid < e1) pm3_body<2>(b.x, b.p, b.N, swt, bid - e0);
    else               pm3_body<2>(c.x, c.p, c.N, swt, bid - e1);
}

// fuseB: L0 u/m aggregation || L1 t-src projection (independent, complementary pipes)
__global__ __launch_bounds__(256, 8) void k_fuseB(FGA u, FGA mm, int e0, PMX pt, int Fb, int T) {
    __shared__ bf16 swt[8192];
    int bid = blockIdx.x;
    int fA  = (int)(((long long)bid * Fb) / T);
    int fA1 = (int)(((long long)(bid + 1) * Fb) / T);
    if (fA1 > fA) {
        if (fA < e0) fagg3_body<2, 8>(u, fA);
        else         fagg3_body<2, 8>(mm, fA - e0);
    } else {
        pm3_body<1>(pt.x, pt.p, pt.N, swt, bid - fA);
    }
}

// two single-relation projections (L1 u-src, m-src)
__global__ __launch_bounds__(256, 8) void k_pmf1s(PMX a, PMX b, int e0) {
    __shared__ bf16 swt[8192];
    int bid = blockIdx.x;
    if (bid < e0) pm3_body<1>(a.x, a.p, a.N, swt, bid);
    else          pm3_body<1>(b.x, b.p, b.N, swt, bid - e0);
}

// single 3-relation aggregation (L0 t-group / L1 t-group)
__global__ void k_fagg1(FGA a) {
    fagg3_body<3, 4>(a, blockIdx.x);
}

__global__ void k_fill_all(Segs s, int TE, const int* __restrict__ rp_all,
                           const unsigned* __restrict__ degp,
                           const int* __restrict__ rank, int* __restrict__ col) {
    fill_body(s, TE, rp_all, degp, rank, col, blockIdx.x);
}

// ================= small kernels =================
__global__ void k_zero_i(int* __restrict__ p, int n) {
    int i = blockIdx.x * 256 + threadIdx.x;
    if (i < n) p[i] = 0;
}

__global__ void k_mkrp(const int* __restrict__ cnt3, int* __restrict__ cnt,
                       unsigned* __restrict__ degp) {
    int i = blockIdx.x * 256 + threadIdx.x;
    int TN = NU + NT + NM;
    if (i >= TN) return;
    int b3, N, n, nrel;
    if (i < NU)            { b3 = 3 * NT;            N = NU; n = i;            nrel = 2; }
    else if (i < NU + NT)  { b3 = 0;                 N = NT; n = i - NU;       nrel = 3; }
    else                   { b3 = 3 * NT + 2 * NU;   N = NM; n = i - NU - NT;  nrel = 2; }
    int d0 = cnt3[b3 + n];
    int d1 = cnt3[b3 + N + n];
    int d2 = (nrel == 3) ? cnt3[b3 + 2 * N + n] : 0;
    cnt[i] = d0 + d1 + d2;
    degp[i] = (unsigned)d0 | ((unsigned)d1 << 10) | ((unsigned)d2 << 20);
}

__global__ void k_scan1(const int* __restrict__ cnt, int n, int* __restrict__ bsum) {
    __shared__ int sh[256];
    int i = blockIdx.x * 256 + threadIdx.x;
    sh[threadIdx.x] = (i < n) ? cnt[i] : 0;
    __syncthreads();
    for (int o = 128; o; o >>= 1) {
        if (threadIdx.x < o) sh[threadIdx.x] += sh[threadIdx.x + o];
        __syncthreads();
    }
    if (threadIdx.x == 0) bsum[blockIdx.x] = sh[0];
}

__global__ void k_scan2(int* __restrict__ bsum, int nb) {  // 1 block
    __shared__ int sh[256];
    __shared__ int carry;
    if (threadIdx.x == 0) carry = 0;
    __syncthreads();
    for (int base = 0; base < nb; base += 256) {
        int i = base + threadIdx.x;
        int v = (i < nb) ? bsum[i] : 0;
        sh[threadIdx.x] = v;
        __syncthreads();
        for (int o = 1; o < 256; o <<= 1) {
            int t = (threadIdx.x >= o) ? sh[threadIdx.x - o] : 0;
            __syncthreads();
            sh[threadIdx.x] += t;
            __syncthreads();
        }
        if (i < nb) bsum[i] = carry + sh[threadIdx.x] - v;  // exclusive
        __syncthreads();
        if (threadIdx.x == 255) carry += sh[255];
        __syncthreads();
    }
}

__global__ void k_scan3(const int* __restrict__ cnt, int n, const int* __restrict__ bsum,
                        int* __restrict__ out) {
    __shared__ int sh[256];
    int i = blockIdx.x * 256 + threadIdx.x;
    int v = (i < n) ? cnt[i] : 0;
    sh[threadIdx.x] = v;
    __syncthreads();
    for (int o = 1; o < 256; o <<= 1) {
        int t = (threadIdx.x >= o) ? sh[threadIdx.x - o] : 0;
        __syncthreads();
        sh[threadIdx.x] += t;
        __syncthreads();
    }
    if (i <= n) out[i] = bsum[blockIdx.x] + sh[threadIdx.x] - v;
}

__global__ void k_wa(const float* __restrict__ lin_w, const float* __restrict__ att_s,
                     const float* __restrict__ att_d, float* __restrict__ was,
                     float* __restrict__ wad) {
    int i = blockIdx.x * 256 + threadIdx.x;
    if (i >= 2 * 7 * 64 * 8) return;
    int j = i & 7;
    int k = (i >> 3) & 63;
    int lr = i >> 9;
    int h = j & 3;
    const float* a = (j < 4 ? att_s : att_d) + lr * 64 + h * 16;
    const float* Wp = lin_w + (size_t)lr * 4096 + k * 64 + h * 16;
    float s = 0.f;
#pragma unroll
    for (int c = 0; c < 16; c++) s += Wp[c] * a[c];
    if (j < 4) was[lr * 256 + k * 4 + h] = s;
    else       wad[lr * 256 + k * 4 + h] = s;
}

__global__ void k_wt(const float* __restrict__ lin_w, bf16* __restrict__ wt) {
    int i = blockIdx.x * 256 + threadIdx.x;
    if (i >= 14 * 4096) return;
    int lr = i >> 12;
    int kc = i & 4095;
    int k = kc >> 6, c = kc & 63;
    float v = lin_w[(size_t)lr * 4096 + k * 64 + c];
    bf16 hi = __float2bfloat16(v);
    float rem = v - __bfloat162float(hi);
    wt[(size_t)lr * 8192 + c * 64 + k] = hi;
    wt[(size_t)lr * 8192 + 4096 + c * 64 + k] = __float2bfloat16(rem);
}

__global__ void k_wtin(const float* __restrict__ Wu, const float* __restrict__ Wt,
                       const float* __restrict__ Wm, bf16* __restrict__ out) {
    int i = blockIdx.x * 256 + threadIdx.x;
    if (i >= 8192) return;
    const float* W; int K, KP, base, j;
    if (i < 2048)      { W = Wu; K = 32; KP = 32; base = 0;     j = i; }
    else if (i < 6144) { W = Wt; K = 64; KP = 64; base = 4096;  j = i - 2048; }
    else               { W = Wm; K = 16; KP = 32; base = 12288; j = i - 6144; }
    int c = j / KP, k = j - c * KP;
    float v = (k < K) ? W[k * 64 + c] : 0.f;
    bf16 hb = __float2bfloat16(v);
    float rem = v - __bfloat162float(hb);
    out[base + c * KP + k] = hb;
    out[base + 64 * KP + c * KP + k] = __float2bfloat16(rem);
}

// ================= classifier =================
__global__ void k_cls(const bf16* __restrict__ t, const float* __restrict__ w1,
                      const float* __restrict__ b1, const float* __restrict__ w2,
                      const float* __restrict__ b2, float* __restrict__ out) {
    __shared__ float w1s[64 * 32];
    __shared__ float w2s[64];
    __shared__ float b1s[32];
    __shared__ float b2s[2];
    __shared__ float ts[8 * 64];
    int tid = threadIdx.x;
    for (int i = tid; i < 2048; i += 256) w1s[i] = w1[i];
    if (tid < 64) w2s[tid] = w2[tid];
    if (tid < 32) b1s[tid] = b1[tid];
    if (tid < 2) b2s[tid] = b2[tid];
    int n0 = blockIdx.x << 3;
    for (int i = tid; i < 512; i += 256) {
        int row = i >> 6, col = i & 63;
        ts[i] = toF(t[(size_t)(n0 + row) * 64 + col]);
    }
    __syncthreads();
    int lane = tid & 31;
    int row = tid >> 5;
    float h = b1s[lane];
#pragma unroll 8
    for (int k = 0; k < 64; k++) h = fmaf(ts[(row << 6) + k], w1s[(k << 5) + lane], h);
    h = h > 0.f ? h : 0.f;
    float o0 = h * w2s[lane * 2 + 0];
    float o1 = h * w2s[lane * 2 + 1];
#pragma unroll
    for (int off = 16; off; off >>= 1) {
        o0 += __shfl_down(o0, off, 32);
        o1 += __shfl_down(o1, off, 32);
    }
    if (lane == 0) {
        int n = n0 + row;
        out[(size_t)n * 2 + 0] = o0 + b2s[0];
        out[(size_t)n * 2 + 1] = o1 + b2s[1];
    }
}

extern "C" void kernel_launch(void* const* d_in, const int* in_sizes, int n_in,
                              void* d_out, int out_size, void* d_ws, size_t ws_size,
                              hipStream_t stream) {
    (void)n_in; (void)out_size;
    const float* x_user  = (const float*)d_in[0];
    const float* x_tx    = (const float*)d_in[1];
    const float* x_merch = (const float*)d_in[2];
    const int* ei[7];
    int E[7];
    for (int r = 0; r < 7; r++) { ei[r] = (const int*)d_in[3 + r]; E[r] = in_sizes[3 + r] / 2; }
    const float* Win_user  = (const float*)d_in[10];
    const float* bin_user  = (const float*)d_in[11];
    const float* Win_tx    = (const float*)d_in[12];
    const float* bin_tx    = (const float*)d_in[13];
    const float* Win_merch = (const float*)d_in[14];
    const float* bin_merch = (const float*)d_in[15];
    const float* lin_w     = (const float*)d_in[16];
    const float* att_src   = (const float*)d_in[17];
    const float* att_dst   = (const float*)d_in[18];
    const float* conv_bias = (const float*)d_in[19];
    const float* cls_w1    = (const float*)d_in[20];
    const float* cls_b1    = (const float*)d_in[21];
    const float* cls_w2    = (const float*)d_in[22];
    const float* cls_b2    = (const float*)d_in[23];

    const int src_type[7] = {0, 1, 2, 1, 0, 2, 1};
    const int dst_type[7] = {1, 0, 1, 2, 0, 2, 1};
    const int N_of[3] = {NU, NT, NM};
    const int type_base[3] = {0, NU, NU + NT};
    const int type3_base[3] = {3 * NT, 0, 3 * NT + 2 * NU};
    const int rel_slot[7] = {0, 0, 1, 0, 1, 1, 2};

    Segs segs;
    int TE = 0;
    int TN = NU + NT + NM;
    int TN3 = 3 * NT + 2 * NU + 2 * NM;
    for (int r = 0; r < 7; r++) {
        segs.ei[r] = ei[r];
        segs.eoff[r] = TE; TE += E[r];
        int dt = dst_type[r];
        segs.n3off[r] = type3_base[dt] + rel_slot[r] * N_of[dt];
        segs.nboff[r] = type_base[dt];
        segs.slot[r] = rel_slot[r];
    }
    segs.eoff[7] = TE;

    // ---- adaptive workspace layout ----
    bf16* A[3]; bf16* hsArr[7];
    float* aS7[7]; float* aD7[7];
    int *rp_all, *col_all, *cnt3, *cnt, *rank, *bsum;
    unsigned* degp;
    float *was, *wad; bf16 *wt, *wtin;
    char* base = (char*)d_ws;
    size_t off;
    auto alloc = [&](size_t bytes) { size_t q = off; off += (bytes + 255) & ~(size_t)255; return q; };
    size_t hs_first;

    auto layout = [&](bool rankReal) -> bool {
        off = 0;
        for (int t = 0; t < 3; t++) A[t] = (bf16*)(base + alloc((size_t)N_of[t] * 128));
        hs_first = (size_t)-1;
        for (int r = 0; r < 7; r++) {
            size_t o = alloc((size_t)N_of[src_type[r]] * 128);
            if (hs_first == (size_t)-1) hs_first = o;
            hsArr[r] = (bf16*)(base + o);
        }
        for (int r = 0; r < 7; r++) aS7[r] = (float*)(base + alloc((size_t)N_of[src_type[r]] * 16));
        for (int r = 0; r < 7; r++) aD7[r] = (float*)(base + alloc((size_t)N_of[dst_type[r]] * 16));
        rp_all  = (int*)(base + alloc(((size_t)TN + 1) * 4));
        degp    = (unsigned*)(base + alloc((size_t)TN * 4));
        col_all = (int*)(base + alloc((size_t)TE * 4));
        bsum    = (int*)(base + alloc((size_t)8192 * 4));
        was     = (float*)(base + alloc((size_t)14 * 256 * 4));
        wad     = (float*)(base + alloc((size_t)14 * 256 * 4));
        wt      = (bf16*)(base + alloc((size_t)14 * 8192 * 2));
        wtin    = (bf16*)(base + alloc((size_t)16384 * 2));
        if (rankReal) rank = (int*)(base + alloc((size_t)TE * 4));
        size_t o_cnt3 = hs_first;
        size_t o_cnt  = o_cnt3 + (((size_t)TN3 * 4 + 255) & ~(size_t)255);
        cnt3 = (int*)(base + o_cnt3);
        cnt  = (int*)(base + o_cnt);
        if (!rankReal) {
            size_t o_rank = o_cnt + (((size_t)TN * 4 + 255) & ~(size_t)255);
            rank = (int*)(base + o_rank);
        }
        return off <= ws_size;
    };
    bool fuseFill = layout(true);
    if (!fuseFill && !layout(false)) return;  // scratch too small: fail cleanly

    // ---- prep ----
    k_wa<<<(7168 + 255) / 256, 256, 0, stream>>>(lin_w, att_src, att_dst, was, wad);
    k_wt<<<(14 * 4096 + 255) / 256, 256, 0, stream>>>(lin_w, wt);
    k_wtin<<<32, 256, 0, stream>>>(Win_user, Win_tx, Win_merch, wtin);
    k_zero_i<<<(TN3 + 255) / 256, 256, 0, stream>>>(cnt3, TN3);

    // ---- fuseA: hist || input projections (Bresenham) ----
    int Hb = (TE + 255) / 256;
    int Pt = (NT + 63) / 64, Pu = (NU + 63) / 64, Pm = (NM + 63) / 64;
    {
        PJ pt = {x_tx, wtin + 4096, bin_tx, A[1], NT};
        PJ pu = {x_user, wtin, bin_user, A[0], NU};
        PJ pm = {x_merch, wtin + 12288, bin_merch, A[2], NM};
        int T = Hb + Pt + Pu + Pm;
        k_fuseA<<<T, 256, 0, stream>>>(segs, TE, cnt3, rank, pt, pu, pm, Hb, T, Pt, Pu);
    }

    // ---- CSR mid chain ----
    int nb = (TN + 256) / 256;
    k_mkrp<<<(TN + 255) / 256, 256, 0, stream>>>(cnt3, cnt, degp);
    k_scan1<<<nb, 256, 0, stream>>>(cnt, TN, bsum);
    k_scan2<<<1, 256, 0, stream>>>(bsum, nb);
    k_scan3<<<nb, 256, 0, stream>>>(cnt, TN, bsum, rp_all);
    if (!fuseFill)
        k_fill_all<<<(TE + 255) / 256, 256, 0, stream>>>(segs, TE, rp_all, degp, rank, col_all);

    const int bat_src[3]     = {1, 0, 2};
    const int bat_rels[3][3] = {{1, 3, 6}, {0, 4, -1}, {2, 5, -1}};
    const int bat_wad[3][2]  = {{0, 2}, {1, -1}, {3, -1}};

    // ================= layer 0 projections (all 7 relations) =================
    {
        int l = 0;
        PMX pmx[3];
        for (int b = 0; b < 3; b++) {
            int st = bat_src[b];
            int nrel = (bat_rels[b][2] >= 0) ? 3 : 2;
            P3 p;
            for (int jj = 0; jj < 3; jj++) {
                int r = bat_rels[b][jj] >= 0 ? bat_rels[b][jj] : bat_rels[b][0];
                int lr = l * 7 + r;
                p.wt[jj]  = wt + (size_t)lr * 8192;
                p.waS[jj] = (const float4*)(was + (size_t)lr * 256);
                p.hs[jj]  = hsArr[r];
                p.aS[jj]  = aS7[r];
            }
            int selfR = bat_rels[b][nrel - 1];
            p.wadL = (const float4*)(wad + (size_t)(l * 7 + selfR) * 256);
            p.aDL  = aD7[selfR];
            int wr0 = bat_wad[b][0], wr1 = bat_wad[b][1];
            p.wadA = (const float4*)(wad + (size_t)(l * 7 + wr0) * 256);
            p.aDA  = aD7[wr0];
            p.wadB = (wr1 >= 0) ? (const float4*)(wad + (size_t)(l * 7 + wr1) * 256) : nullptr;
            p.aDB  = (wr1 >= 0) ? aD7[wr1] : nullptr;
            pmx[b].x = A[st];
            pmx[b].p = p;
            pmx[b].N = N_of[st];
        }
        int b0 = (pmx[0].N + 63) / 64;
        int b1 = (pmx[1].N + 63) / 64;
        int b2 = (pmx[2].N + 63) / 64;
        if (fuseFill) {
            int Fb = (TE + 255) / 256;
            int T = Fb + b0 + b1 + b2;
            k_pmf3xF<<<T, 256, 0, stream>>>(pmx[0], pmx[1], pmx[2], b0, b0 + b1,
                                            segs, TE, rp_all, degp, rank, col_all, Fb, T);
        } else {
            k_pmf3x<<<b0 + b1 + b2, 256, 0, stream>>>(pmx[0], pmx[1], pmx[2], b0, b0 + b1);
        }
    }

    // ================= L0 t-group aggregation =================
    {
        FGA fgt0;
        fgt0.rp   = rp_all + type_base[1];
        fgt0.degp = degp + type_base[1];
        fgt0.col  = col_all;
        fgt0.aS0 = aS7[0]; fgt0.aS1 = aS7[2]; fgt0.aS2 = aS7[6];
        fgt0.aD0 = aD7[0]; fgt0.aD1 = aD7[2]; fgt0.aD2 = aD7[6];
        fgt0.h0 = hsArr[0]; fgt0.h1 = hsArr[2]; fgt0.h2 = hsArr[6];
        fgt0.cb = conv_bias; fgt0.b0 = 0; fgt0.b1 = 2; fgt0.b2 = 6;
        fgt0.out = A[1]; fgt0.Nd = NT;
        k_fagg1<<<(NT + 7) / 8, 256, 0, stream>>>(fgt0);
    }

    // ================= fuseB: L0 u/m aggregation || L1 t-src projection =================
    {
        FGA fu, fm;
        fu.rp   = rp_all + type_base[0];
        fu.degp = degp + type_base[0];
        fu.col  = col_all;
        fu.aS0 = aS7[1]; fu.aS1 = aS7[4]; fu.aS2 = aS7[1];
        fu.aD0 = aD7[1]; fu.aD1 = aD7[4]; fu.aD2 = aD7[1];
        fu.h0 = hsArr[1]; fu.h1 = hsArr[4]; fu.h2 = hsArr[1];
        fu.cb = conv_bias; fu.b0 = 1; fu.b1 = 4; fu.b2 = -1;
        fu.out = A[0]; fu.Nd = NU;
        fm.rp   = rp_all + type_base[2];
        fm.degp = degp + type_base[2];
        fm.col  = col_all;
        fm.aS0 = aS7[3]; fm.aS1 = aS7[5]; fm.aS2 = aS7[3];
        fm.aD0 = aD7[3]; fm.aD1 = aD7[5]; fm.aD2 = aD7[3];
        fm.h0 = hsArr[3]; fm.h1 = hsArr[5]; fm.h2 = hsArr[3];
        fm.cb = conv_bias; fm.b0 = 3; fm.b1 = 5; fm.b2 = -1;
        fm.out = A[2]; fm.Nd = NM;

        PMX pt;
        {
            P3 p = {};
            int lr = 7 + 6;
            p.wt[0]  = wt + (size_t)lr * 8192;
            p.waS[0] = (const float4*)(was + (size_t)lr * 256);
            p.hs[0]  = hsArr[6];
            p.aS[0]  = aS7[6];
            p.wadL = (const float4*)(wad + (size_t)lr * 256);
            p.aDL  = aD7[6];
            p.wadA = (const float4*)(wad + (size_t)(7 + 0) * 256);
            p.aDA  = aD7[0];
            p.wadB = (const float4*)(wad + (size_t)(7 + 2) * 256);
            p.aDB  = aD7[2];
            pt.x = A[1]; pt.p = p; pt.N = NT;
        }
        int ub = (NU + 7) / 8;
        int mb = (NM + 7) / 8;
        int Fb = ub + mb;
        int Pb = (NT + 63) / 64;
        int T = Fb + Pb;
        k_fuseB<<<T, 256, 0, stream>>>(fu, fm, ub, pt, Fb, T);
    }

    // ================= L1 u-src, m-src projections =================
    {
        PMX pu, pm;
        {
            P3 p = {};
            int lr = 7 + 0;
            p.wt[0]  = wt + (size_t)lr * 8192;
            p.waS[0] = (const float4*)(was + (size_t)lr * 256);
            p.hs[0]  = hsArr[0];
            p.aS[0]  = aS7[0];
            pu.x = A[0]; pu.p = p; pu.N = NU;
        }
        {
            P3 p = {};
            int lr = 7 + 2;
            p.wt[0]  = wt + (size_t)lr * 8192;
            p.waS[0] = (const float4*)(was + (size_t)lr * 256);
            p.hs[0]  = hsArr[2];
            p.aS[0]  = aS7[2];
            pm.x = A[2]; pm.p = p; pm.N = NM;
        }
        int b0 = (NU + 63) / 64;
        int b1 = (NM + 63) / 64;
        k_pmf1s<<<b0 + b1, 256, 0, stream>>>(pu, pm, b0);
    }

    // ================= L1 t-group aggregation =================
    {
        FGA a;
        a.rp   = rp_all + type_base[1];
        a.degp = degp + type_base[1];
        a.col  = col_all;
        a.aS0 = aS7[0]; a.aS1 = aS7[2]; a.aS2 = aS7[6];
        a.aD0 = aD7[0]; a.aD1 = aD7[2]; a.aD2 = aD7[6];
        a.h0 = hsArr[0]; a.h1 = hsArr[2]; a.h2 = hsArr[6];
        a.cb = conv_bias + (size_t)7 * 64; a.b0 = 0; a.b1 = 2; a.b2 = 6;
        a.out = A[1]; a.Nd = NT;
        k_fagg1<<<(NT + 7) / 8, 256, 0, stream>>>(a);
    }
    k_cls<<<NT / 8, 256, 0, stream>>>(A[1], cls_w1, cls_b1, cls_w2, cls_b2, (float*)d_out);
}

// Round 26
// 670.974 us; speedup vs baseline: 1.0488x; 1.0051x over previous
//
#include <hip/hip_runtime.h>
#include <hip/hip_bf16.h>

#define NU 100000
#define NT 300000
#define NM 10000

typedef __hip_bfloat16 bf16;
typedef __attribute__((ext_vector_type(8))) short bf16x8;
typedef __attribute__((ext_vector_type(4))) float f32x4;

__device__ __forceinline__ float toF(float v) { return v; }
__device__ __forceinline__ float toF(bf16 v)  { return __bfloat162float(v); }
__device__ __forceinline__ float bitsLo(unsigned u) { return __uint_as_float(u << 16); }
__device__ __forceinline__ float bitsHi(unsigned u) { return __uint_as_float(u & 0xffff0000u); }
__device__ __forceinline__ float shortBF(short s) { return __uint_as_float(((unsigned)(unsigned short)s) << 16); }
__device__ __forceinline__ short bfBits(float v) { bf16 b = __float2bfloat16(v); return *(short*)&b; }
__device__ __forceinline__ int rd16(const unsigned* __restrict__ c3, int idx) {
    return (int)((c3[idx >> 1] >> ((idx & 1) * 16)) & 0xFFFFu);
}

struct Segs {
    const int* ei[7];
    int eoff[8];
    int n3off[8];
    int nboff[8];
    int slot[8];
};

struct P3 {
    const bf16* wt[3];
    const float4* waS[3];
    bf16* hs[3];
    float* aS[3];
    const float4* wadL; float* aDL;   // nullable
    const float4* wadA; float* aDA;
    const float4* wadB; float* aDB;
};

struct PJ { const float* x; const bf16* wt; const float* bias; bf16* out; int N; };
struct PMX { const bf16* x; P3 p; int N; };
struct FGA {
    const int* rp; const unsigned* degp; const int* col;
    const float *aS0, *aS1, *aS2;
    const float *aD0, *aD1, *aD2;
    const bf16 *h0, *h1, *h2;
    const float* cb; int b0, b1, b2; bf16* out; int Nd;
};

// ================= device bodies =================
__device__ __forceinline__ void hist_body(const Segs& s, int TE, unsigned* __restrict__ cnt3,
                                          int* __restrict__ rank, int bid) {
    int g = bid * 256 + threadIdx.x;
    if (g >= TE) return;
    int r = 0;
    while (g >= s.eoff[r + 1]) r++;
    int e = g - s.eoff[r];
    int E = s.eoff[r + 1] - s.eoff[r];
    int d = s.ei[r][E + e];
    int idx = s.n3off[r] + d;
    unsigned sh = (idx & 1) * 16;
    unsigned old = atomicAdd(&cnt3[idx >> 1], 1u << sh);
    rank[g] = (int)((old >> sh) & 0xFFFFu);
}

__device__ __forceinline__ void fill_body(const Segs& s, int TE, const int* __restrict__ rp_all,
                                          const unsigned* __restrict__ degp,
                                          const int* __restrict__ rank, int* __restrict__ col,
                                          int bid) {
    int g = bid * 256 + threadIdx.x;
    if (g >= TE) return;
    int r = 0;
    while (g >= s.eoff[r + 1]) r++;
    int e = g - s.eoff[r];
    int E = s.eoff[r + 1] - s.eoff[r];
    int d = s.ei[r][E + e];
    int ni = s.nboff[r] + d;
    unsigned dp = degp[ni];
    int sl = s.slot[r];
    int segoff = (sl == 0) ? 0 : ((sl == 1) ? (int)(dp & 1023)
                                            : (int)((dp & 1023) + ((dp >> 10) & 1023)));
    col[rp_all[ni] + segoff + rank[g]] = s.ei[r][e];
}

template <int K>
__device__ __forceinline__ void projm_body(const float* __restrict__ x, const bf16* __restrict__ wt,
                                           const float* __restrict__ bias, bf16* __restrict__ out,
                                           int N, int bid) {
    constexpr int KP = (K > 32) ? 64 : 32;
    int w = threadIdx.x >> 6, lane = threadIdx.x & 63;
    int m = lane & 15, kq = lane >> 4;
    int r0 = bid * 64 + w * 16;
    int row = r0 + m;
    bf16x8 ah0 = {}, al0 = {}, ah1 = {}, al1 = {};
    if (row < N) {
#pragma unroll
        for (int j = 0; j < 8; j++) {
            int k = kq * 8 + j;
            float v = (k < K) ? x[(size_t)row * K + k] : 0.f;
            short hb = bfBits(v);
            ah0[j] = hb;
            al0[j] = bfBits(v - shortBF(hb));
        }
        if (KP == 64) {
#pragma unroll
            for (int j = 0; j < 8; j++) {
                float v = x[(size_t)row * K + 32 + kq * 8 + j];
                short hb = bfBits(v);
                ah1[j] = hb;
                al1[j] = bfBits(v - shortBF(hb));
            }
        }
    }
#pragma unroll
    for (int nt = 0; nt < 4; nt++) {
        int c = nt * 16 + m;
        f32x4 acc = {};
        const bf16* bh = wt + c * KP + kq * 8;
        const bf16* bl = wt + 64 * KP + c * KP + kq * 8;
        bf16x8 bh0 = *(const bf16x8*)(bh);
        bf16x8 bl0 = *(const bf16x8*)(bl);
        acc = __builtin_amdgcn_mfma_f32_16x16x32_bf16(ah0, bh0, acc, 0, 0, 0);
        acc = __builtin_amdgcn_mfma_f32_16x16x32_bf16(al0, bh0, acc, 0, 0, 0);
        acc = __builtin_amdgcn_mfma_f32_16x16x32_bf16(ah0, bl0, acc, 0, 0, 0);
        if (KP == 64) {
            bf16x8 bh1 = *(const bf16x8*)(bh + 32);
            bf16x8 bl1 = *(const bf16x8*)(bl + 32);
            acc = __builtin_amdgcn_mfma_f32_16x16x32_bf16(ah1, bh1, acc, 0, 0, 0);
            acc = __builtin_amdgcn_mfma_f32_16x16x32_bf16(al1, bh1, acc, 0, 0, 0);
            acc = __builtin_amdgcn_mfma_f32_16x16x32_bf16(ah1, bl1, acc, 0, 0, 0);
        }
        float bv = bias[c];
#pragma unroll
        for (int i = 0; i < 4; i++) {
            int rr = r0 + kq * 4 + i;
            if (rr < N) out[(size_t)rr * 64 + c] = __float2bfloat16(acc[i] + bv);
        }
    }
}

__device__ __forceinline__ void alpha_gemv(const float4* __restrict__ w4,
                                           const float* __restrict__ xv,
                                           int kq, int row, int N,
                                           float* __restrict__ out) {
    float p0 = 0.f, p1 = 0.f, p2 = 0.f, p3 = 0.f;
#pragma unroll
    for (int kk = 0; kk < 8; kk++) {
        float4 wA = w4[kq * 8 + kk];
        p0 = fmaf(xv[kk], wA.x, p0); p1 = fmaf(xv[kk], wA.y, p1);
        p2 = fmaf(xv[kk], wA.z, p2); p3 = fmaf(xv[kk], wA.w, p3);
        float4 wB = w4[32 + kq * 8 + kk];
        p0 = fmaf(xv[8 + kk], wB.x, p0); p1 = fmaf(xv[8 + kk], wB.y, p1);
        p2 = fmaf(xv[8 + kk], wB.z, p2); p3 = fmaf(xv[8 + kk], wB.w, p3);
    }
    p0 += __shfl_xor(p0, 16); p0 += __shfl_xor(p0, 32);
    p1 += __shfl_xor(p1, 16); p1 += __shfl_xor(p1, 32);
    p2 += __shfl_xor(p2, 16); p2 += __shfl_xor(p2, 32);
    p3 += __shfl_xor(p3, 16); p3 += __shfl_xor(p3, 32);
    if (kq == 0 && row < N) {
        float4 o; o.x = p0; o.y = p1; o.z = p2; o.w = p3;
        *(float4*)(out + (size_t)row * 4) = o;
    }
}

template <int NREL>
__device__ __forceinline__ void pm3_body(const bf16* __restrict__ x, const P3& p, int N,
                                         bf16* swt, int bid) {
    int tid = threadIdx.x;
    int w = tid >> 6, lane = tid & 63;
    int m = lane & 15, kq = lane >> 4;
    int r0 = bid * 64 + w * 16;
    bf16x8 a0 = {}, a1 = {};
    int row = r0 + m;
    if (row < N) {
        a0 = *(const bf16x8*)(x + (size_t)row * 64 + kq * 8);
        a1 = *(const bf16x8*)(x + (size_t)row * 64 + 32 + kq * 8);
    }
    auto ldw = [&](int r, int b) -> bf16x8 {
        int sb = b ^ ((r & 7) << 4);
        return *(const bf16x8*)((const char*)swt + r * 128 + sb);
    };
#pragma unroll
    for (int rl = 0; rl < NREL; rl++) {
        __syncthreads();
        {
            const uint4* src = (const uint4*)p.wt[rl];
            for (int i = tid; i < 1024; i += 256) {
                int r = i >> 3, b = (i & 7) << 4;
                int sb = b ^ ((r & 7) << 4);
                *(uint4*)((char*)swt + r * 128 + sb) = src[i];
            }
        }
        __syncthreads();
        bf16* hs = p.hs[rl];
#pragma unroll
        for (int nt = 0; nt < 4; nt++) {
            int rw = nt * 16 + m;
            bf16x8 bh0 = ldw(rw, kq * 16);
            bf16x8 bh1 = ldw(rw, kq * 16 + 64);
            bf16x8 bl0 = ldw(64 + rw, kq * 16);
            bf16x8 bl1 = ldw(64 + rw, kq * 16 + 64);
            f32x4 acc = {};
            acc = __builtin_amdgcn_mfma_f32_16x16x32_bf16(a0, bh0, acc, 0, 0, 0);
            acc = __builtin_amdgcn_mfma_f32_16x16x32_bf16(a0, bl0, acc, 0, 0, 0);
            acc = __builtin_amdgcn_mfma_f32_16x16x32_bf16(a1, bh1, acc, 0, 0, 0);
            acc = __builtin_amdgcn_mfma_f32_16x16x32_bf16(a1, bl1, acc, 0, 0, 0);
#pragma unroll
            for (int i = 0; i < 4; i++) {
                int rr = r0 + kq * 4 + i;
                if (rr < N) hs[(size_t)rr * 64 + nt * 16 + m] = __float2bfloat16(acc[i]);
            }
        }
    }
    float xv[16];
#pragma unroll
    for (int kk = 0; kk < 8; kk++) { xv[kk] = shortBF(a0[kk]); xv[8 + kk] = shortBF(a1[kk]); }
#pragma unroll
    for (int rl = 0; rl < NREL; rl++)
        alpha_gemv(p.waS[rl], xv, kq, row, N, p.aS[rl]);
    if (p.wadL) alpha_gemv(p.wadL, xv, kq, row, N, p.aDL);
    if (p.wadA) alpha_gemv(p.wadA, xv, kq, row, N, p.aDA);
    if (p.wadB) alpha_gemv(p.wadB, xv, kq, row, N, p.aDB);
}

template <int EPR>
__device__ __forceinline__ void seg_agg(const int* __restrict__ col, int s, int d,
                                        const float* __restrict__ aS, float adv,
                                        const bf16* __restrict__ hp,
                                        int l32, int hcl, float& ox, float& oy) {
    float dn = 0.f, ax = 0.f, ay = 0.f;
    for (int i0 = 0; i0 < d; i0 += EPR) {
        int mrem = d - i0;
        int cw[EPR];
#pragma unroll
        for (int j = 0; j < EPR; j++) cw[j] = (j < mrem) ? col[s + i0 + j] : 0;
        float as[EPR];
#pragma unroll
        for (int j = 0; j < EPR; j++) as[j] = (j < mrem) ? aS[cw[j] * 4 + hcl] : 0.f;
        unsigned hv[EPR];
#pragma unroll
        for (int j = 0; j < EPR; j++)
            hv[j] = (j < mrem) ? *(const unsigned*)(hp + (size_t)cw[j] * 64 + 2 * l32) : 0u;
#pragma unroll
        for (int j = 0; j < EPR; j++) if (j < mrem) {
            float a = as[j] + adv;
            a = (a >= 0.f) ? a : 0.2f * a;
            float ex = __expf(a);
            dn += ex;
            ax = fmaf(ex, bitsLo(hv[j]), ax);
            ay = fmaf(ex, bitsHi(hv[j]), ay);
        }
    }
    float rd = 1.f / (dn + 1e-16f);
    ox = fmaf(ax, rd, ox);
    oy = fmaf(ay, rd, oy);
}

template <int NREL, int EPR>
__device__ __forceinline__ void fagg3_body(const FGA& a, int bid) {
    int tid = threadIdx.x;
    int wv = tid >> 6, lane = tid & 63;
    int half = lane >> 5, l32 = lane & 31;
    int node = bid * 8 + wv * 2 + half;
    bool alive = node < a.Nd;
    int nc = alive ? node : (a.Nd - 1);
    int hcl = l32 >> 3;
    int s = a.rp[nc];
    unsigned dp = a.degp[nc];
    int d0 = dp & 1023, d1 = (dp >> 10) & 1023, d2 = (dp >> 20) & 1023;
    float2 bb = *(const float2*)(a.cb + a.b0 * 64 + 2 * l32);
    float ox = bb.x, oy = bb.y;
    if (a.b1 >= 0) { float2 t = *(const float2*)(a.cb + a.b1 * 64 + 2 * l32); ox += t.x; oy += t.y; }
    if (a.b2 >= 0) { float2 t = *(const float2*)(a.cb + a.b2 * 64 + 2 * l32); ox += t.x; oy += t.y; }
    seg_agg<EPR>(a.col, s, d0, a.aS0, a.aD0[nc * 4 + hcl], a.h0, l32, hcl, ox, oy);
    seg_agg<EPR>(a.col, s + d0, d1, a.aS1, a.aD1[nc * 4 + hcl], a.h1, l32, hcl, ox, oy);
    if (NREL > 2)
        seg_agg<EPR>(a.col, s + d0 + d1, d2, a.aS2, a.aD2[nc * 4 + hcl], a.h2, l32, hcl, ox, oy);
    ox = ox > 0.f ? ox : 0.f;
    oy = oy > 0.f ? oy : 0.f;
    if (alive) {
        bf16 p0 = __float2bfloat16(ox), p1 = __float2bfloat16(oy);
        unsigned pk = ((unsigned)(*(unsigned short*)&p1) << 16) | (unsigned)(*(unsigned short*)&p0);
        ((unsigned*)a.out)[(size_t)node * 32 + l32] = pk;
    }
}

// ================= fused kernels =================
__global__ void k_fuseA(Segs s, int TE, unsigned* cnt3, int* rank,
                        PJ pt, PJ pu, PJ pm, int Hb, int T, int Pt, int Pu) {
    int bid = blockIdx.x;
    int hA  = (int)(((long long)bid * Hb) / T);
    int hA1 = (int)(((long long)(bid + 1) * Hb) / T);
    if (hA1 > hA) {
        hist_body(s, TE, cnt3, rank, hA);
    } else {
        int pidx = bid - hA;
        if (pidx < Pt)            projm_body<64>(pt.x, pt.wt, pt.bias, pt.out, pt.N, pidx);
        else if (pidx < Pt + Pu)  projm_body<32>(pu.x, pu.wt, pu.bias, pu.out, pu.N, pidx - Pt);
        else                      projm_body<16>(pm.x, pm.wt, pm.bias, pm.out, pm.N, pidx - Pt - Pu);
    }
}

// layer-0 fused: CSR fill || triple projection (Bresenham)
__global__ __launch_bounds__(256, 8) void k_pmf3xF(PMX a, PMX b, PMX c, int e0, int e1,
                                                   Segs s, int TE, const int* rp_all,
                                                   const unsigned* degp, const int* rank,
                                                   int* col, int Fb, int T) {
    __shared__ bf16 swt[8192];
    int bid = blockIdx.x;
    int fA  = (int)(((long long)bid * Fb) / T);
    int fA1 = (int)(((long long)(bid + 1) * Fb) / T);
    if (fA1 > fA) {
        fill_body(s, TE, rp_all, degp, rank, col, fA);
    } else {
        int pidx = bid - fA;
        if (pidx < e0)      pm3_body<3>(a.x, a.p, a.N, swt, pidx);
        else if (pidx < e1) pm3_body<2>(b.x, b.p, b.N, swt, pidx - e0);
        else                pm3_body<2>(c.x, c.p, c.N, swt, pidx - e1);
    }
}

// plain fused triple projection (layer-0 fallback)
__global__ __launch_bounds__(256, 8) void k_pmf3x(PMX a, PMX b, PMX c, int e0, int e1) {
    __shared__ bf16 swt[8192];
    int bid = blockIdx.x;
    if (bid < e0)      pm3_body<3>(a.x, a.p, a.N, swt, bid);
    else if (bid < e1) pm3_body<2>(b.x, b.p, b.N, swt, bid - e0);
    else               pm3_body<2>(c.x, c.p, c.N, swt, bid - e1);
}

// fuseB: L0 u/m aggregation || L1 t-src projection
__global__ __launch_bounds__(256, 8) void k_fuseB(FGA u, FGA mm, int e0, PMX pt, int Fb, int T) {
    __shared__ bf16 swt[8192];
    int bid = blockIdx.x;
    int fA  = (int)(((long long)bid * Fb) / T);
    int fA1 = (int)(((long long)(bid + 1) * Fb) / T);
    if (fA1 > fA) {
        if (fA < e0) fagg3_body<2, 8>(u, fA);
        else         fagg3_body<2, 8>(mm, fA - e0);
    } else {
        pm3_body<1>(pt.x, pt.p, pt.N, swt, bid - fA);
    }
}

// two single-relation projections (L1 u-src, m-src)
__global__ __launch_bounds__(256, 8) void k_pmf1s(PMX a, PMX b, int e0) {
    __shared__ bf16 swt[8192];
    int bid = blockIdx.x;
    if (bid < e0) pm3_body<1>(a.x, a.p, a.N, swt, bid);
    else          pm3_body<1>(b.x, b.p, b.N, swt, bid - e0);
}

// single 3-relation aggregation (L0 t-group / L1 t-group)
__global__ void k_fagg1(FGA a) {
    fagg3_body<3, 4>(a, blockIdx.x);
}

__global__ void k_fill_all(Segs s, int TE, const int* __restrict__ rp_all,
                           const unsigned* __restrict__ degp,
                           const int* __restrict__ rank, int* __restrict__ col) {
    fill_body(s, TE, rp_all, degp, rank, col, blockIdx.x);
}

// ================= small kernels =================
__global__ void k_zero_u(unsigned* __restrict__ p, int n) {
    int i = blockIdx.x * 256 + threadIdx.x;
    if (i < n) p[i] = 0u;
}

// scan1 merged with mkrp: reads packed cnt3, emits cnt, degp, per-block sums
__global__ void k_scan1m(const unsigned* __restrict__ cnt3, int n, int* __restrict__ bsum,
                         int* __restrict__ cnt, unsigned* __restrict__ degp) {
    __shared__ int sh[256];
    int i = blockIdx.x * 256 + threadIdx.x;
    int tot = 0;
    if (i < n) {
        int b3, N, nn, nrel;
        if (i < NU)            { b3 = 3 * NT;            N = NU; nn = i;            nrel = 2; }
        else if (i < NU + NT)  { b3 = 0;                 N = NT; nn = i - NU;       nrel = 3; }
        else                   { b3 = 3 * NT + 2 * NU;   N = NM; nn = i - NU - NT;  nrel = 2; }
        int d0 = rd16(cnt3, b3 + nn);
        int d1 = rd16(cnt3, b3 + N + nn);
        int d2 = (nrel == 3) ? rd16(cnt3, b3 + 2 * N + nn) : 0;
        tot = d0 + d1 + d2;
        cnt[i] = tot;
        degp[i] = (unsigned)d0 | ((unsigned)d1 << 10) | ((unsigned)d2 << 20);
    }
    sh[threadIdx.x] = tot;
    __syncthreads();
    for (int o = 128; o; o >>= 1) {
        if (threadIdx.x < o) sh[threadIdx.x] += sh[threadIdx.x + o];
        __syncthreads();
    }
    if (threadIdx.x == 0) bsum[blockIdx.x] = sh[0];
}

__global__ void k_scan2(int* __restrict__ bsum, int nb) {  // 1 block
    __shared__ int sh[256];
    __shared__ int carry;
    if (threadIdx.x == 0) carry = 0;
    __syncthreads();
    for (int base = 0; base < nb; base += 256) {
        int i = base + threadIdx.x;
        int v = (i < nb) ? bsum[i] : 0;
        sh[threadIdx.x] = v;
        __syncthreads();
        for (int o = 1; o < 256; o <<= 1) {
            int t = (threadIdx.x >= o) ? sh[threadIdx.x - o] : 0;
            __syncthreads();
            sh[threadIdx.x] += t;
            __syncthreads();
        }
        if (i < nb) bsum[i] = carry + sh[threadIdx.x] - v;  // exclusive
        __syncthreads();
        if (threadIdx.x == 255) carry += sh[255];
        __syncthreads();
    }
}

__global__ void k_scan3(const int* __restrict__ cnt, int n, const int* __restrict__ bsum,
                        int* __restrict__ out) {
    __shared__ int sh[256];
    int i = blockIdx.x * 256 + threadIdx.x;
    int v = (i < n) ? cnt[i] : 0;
    sh[threadIdx.x] = v;
    __syncthreads();
    for (int o = 1; o < 256; o <<= 1) {
        int t = (threadIdx.x >= o) ? sh[threadIdx.x - o] : 0;
        __syncthreads();
        sh[threadIdx.x] += t;
        __syncthreads();
    }
    if (i <= n) out[i] = bsum[blockIdx.x] + sh[threadIdx.x] - v;
}

__global__ void k_wa(const float* __restrict__ lin_w, const float* __restrict__ att_s,
                     const float* __restrict__ att_d, float* __restrict__ was,
                     float* __restrict__ wad) {
    int i = blockIdx.x * 256 + threadIdx.x;
    if (i >= 2 * 7 * 64 * 8) return;
    int j = i & 7;
    int k = (i >> 3) & 63;
    int lr = i >> 9;
    int h = j & 3;
    const float* a = (j < 4 ? att_s : att_d) + lr * 64 + h * 16;
    const float* Wp = lin_w + (size_t)lr * 4096 + k * 64 + h * 16;
    float s = 0.f;
#pragma unroll
    for (int c = 0; c < 16; c++) s += Wp[c] * a[c];
    if (j < 4) was[lr * 256 + k * 4 + h] = s;
    else       wad[lr * 256 + k * 4 + h] = s;
}

__global__ void k_wt(const float* __restrict__ lin_w, bf16* __restrict__ wt) {
    int i = blockIdx.x * 256 + threadIdx.x;
    if (i >= 14 * 4096) return;
    int lr = i >> 12;
    int kc = i & 4095;
    int k = kc >> 6, c = kc & 63;
    float v = lin_w[(size_t)lr * 4096 + k * 64 + c];
    bf16 hi = __float2bfloat16(v);
    float rem = v - __bfloat162float(hi);
    wt[(size_t)lr * 8192 + c * 64 + k] = hi;
    wt[(size_t)lr * 8192 + 4096 + c * 64 + k] = __float2bfloat16(rem);
}

__global__ void k_wtin(const float* __restrict__ Wu, const float* __restrict__ Wt,
                       const float* __restrict__ Wm, bf16* __restrict__ out) {
    int i = blockIdx.x * 256 + threadIdx.x;
    if (i >= 8192) return;
    const float* W; int K, KP, base, j;
    if (i < 2048)      { W = Wu; K = 32; KP = 32; base = 0;     j = i; }
    else if (i < 6144) { W = Wt; K = 64; KP = 64; base = 4096;  j = i - 2048; }
    else               { W = Wm; K = 16; KP = 32; base = 12288; j = i - 6144; }
    int c = j / KP, k = j - c * KP;
    float v = (k < K) ? W[k * 64 + c] : 0.f;
    bf16 hb = __float2bfloat16(v);
    float rem = v - __bfloat162float(hb);
    out[base + c * KP + k] = hb;
    out[base + 64 * KP + c * KP + k] = __float2bfloat16(rem);
}

// ================= classifier =================
__global__ void k_cls(const bf16* __restrict__ t, const float* __restrict__ w1,
                      const float* __restrict__ b1, const float* __restrict__ w2,
                      const float* __restrict__ b2, float* __restrict__ out) {
    __shared__ float w1s[64 * 32];
    __shared__ float w2s[64];
    __shared__ float b1s[32];
    __shared__ float b2s[2];
    __shared__ float ts[8 * 64];
    int tid = threadIdx.x;
    for (int i = tid; i < 2048; i += 256) w1s[i] = w1[i];
    if (tid < 64) w2s[tid] = w2[tid];
    if (tid < 32) b1s[tid] = b1[tid];
    if (tid < 2) b2s[tid] = b2[tid];
    int n0 = blockIdx.x << 3;
    for (int i = tid; i < 512; i += 256) {
        int row = i >> 6, col = i & 63;
        ts[i] = toF(t[(size_t)(n0 + row) * 64 + col]);
    }
    __syncthreads();
    int lane = tid & 31;
    int row = tid >> 5;
    float h = b1s[lane];
#pragma unroll 8
    for (int k = 0; k < 64; k++) h = fmaf(ts[(row << 6) + k], w1s[(k << 5) + lane], h);
    h = h > 0.f ? h : 0.f;
    float o0 = h * w2s[lane * 2 + 0];
    float o1 = h * w2s[lane * 2 + 1];
#pragma unroll
    for (int off = 16; off; off >>= 1) {
        o0 += __shfl_down(o0, off, 32);
        o1 += __shfl_down(o1, off, 32);
    }
    if (lane == 0) {
        int n = n0 + row;
        out[(size_t)n * 2 + 0] = o0 + b2s[0];
        out[(size_t)n * 2 + 1] = o1 + b2s[1];
    }
}

extern "C" void kernel_launch(void* const* d_in, const int* in_sizes, int n_in,
                              void* d_out, int out_size, void* d_ws, size_t ws_size,
                              hipStream_t stream) {
    (void)n_in; (void)out_size;
    const float* x_user  = (const float*)d_in[0];
    const float* x_tx    = (const float*)d_in[1];
    const float* x_merch = (const float*)d_in[2];
    const int* ei[7];
    int E[7];
    for (int r = 0; r < 7; r++) { ei[r] = (const int*)d_in[3 + r]; E[r] = in_sizes[3 + r] / 2; }
    const float* Win_user  = (const float*)d_in[10];
    const float* bin_user  = (const float*)d_in[11];
    const float* Win_tx    = (const float*)d_in[12];
    const float* bin_tx    = (const float*)d_in[13];
    const float* Win_merch = (const float*)d_in[14];
    const float* bin_merch = (const float*)d_in[15];
    const float* lin_w     = (const float*)d_in[16];
    const float* att_src   = (const float*)d_in[17];
    const float* att_dst   = (const float*)d_in[18];
    const float* conv_bias = (const float*)d_in[19];
    const float* cls_w1    = (const float*)d_in[20];
    const float* cls_b1    = (const float*)d_in[21];
    const float* cls_w2    = (const float*)d_in[22];
    const float* cls_b2    = (const float*)d_in[23];

    const int src_type[7] = {0, 1, 2, 1, 0, 2, 1};
    const int dst_type[7] = {1, 0, 1, 2, 0, 2, 1};
    const int N_of[3] = {NU, NT, NM};
    const int type_base[3] = {0, NU, NU + NT};
    const int type3_base[3] = {3 * NT, 0, 3 * NT + 2 * NU};
    const int rel_slot[7] = {0, 0, 1, 0, 1, 1, 2};

    Segs segs;
    int TE = 0;
    int TN = NU + NT + NM;
    int TN3 = 3 * NT + 2 * NU + 2 * NM;
    int TN3w = (TN3 + 1) / 2;
    for (int r = 0; r < 7; r++) {
        segs.ei[r] = ei[r];
        segs.eoff[r] = TE; TE += E[r];
        int dt = dst_type[r];
        segs.n3off[r] = type3_base[dt] + rel_slot[r] * N_of[dt];
        segs.nboff[r] = type_base[dt];
        segs.slot[r] = rel_slot[r];
    }
    segs.eoff[7] = TE;

    // ---- adaptive workspace layout ----
    bf16* A[3]; bf16* hsArr[7];
    float* aS7[7]; float* aD7[7];
    int *rp_all, *col_all, *cnt, *rank, *bsum;
    unsigned *cnt3, *degp;
    float *was, *wad; bf16 *wt, *wtin;
    char* base = (char*)d_ws;
    size_t off;
    auto alloc = [&](size_t bytes) { size_t q = off; off += (bytes + 255) & ~(size_t)255; return q; };
    size_t hs_first;

    auto layout = [&](bool rankReal) -> bool {
        off = 0;
        for (int t = 0; t < 3; t++) A[t] = (bf16*)(base + alloc((size_t)N_of[t] * 128));
        hs_first = (size_t)-1;
        for (int r = 0; r < 7; r++) {
            size_t o = alloc((size_t)N_of[src_type[r]] * 128);
            if (hs_first == (size_t)-1) hs_first = o;
            hsArr[r] = (bf16*)(base + o);
        }
        for (int r = 0; r < 7; r++) aS7[r] = (float*)(base + alloc((size_t)N_of[src_type[r]] * 16));
        for (int r = 0; r < 7; r++) aD7[r] = (float*)(base + alloc((size_t)N_of[dst_type[r]] * 16));
        rp_all  = (int*)(base + alloc(((size_t)TN + 1) * 4));
        degp    = (unsigned*)(base + alloc((size_t)TN * 4));
        col_all = (int*)(base + alloc((size_t)TE * 4));
        bsum    = (int*)(base + alloc((size_t)8192 * 4));
        was     = (float*)(base + alloc((size_t)14 * 256 * 4));
        wad     = (float*)(base + alloc((size_t)14 * 256 * 4));
        wt      = (bf16*)(base + alloc((size_t)14 * 8192 * 2));
        wtin    = (bf16*)(base + alloc((size_t)16384 * 2));
        if (rankReal) rank = (int*)(base + alloc((size_t)TE * 4));
        size_t o_cnt3 = hs_first;
        size_t o_cnt  = o_cnt3 + (((size_t)TN3w * 4 + 255) & ~(size_t)255);
        cnt3 = (unsigned*)(base + o_cnt3);
        cnt  = (int*)(base + o_cnt);
        if (!rankReal) {
            size_t o_rank = o_cnt + (((size_t)TN * 4 + 255) & ~(size_t)255);
            rank = (int*)(base + o_rank);
        }
        return off <= ws_size;
    };
    bool fuseFill = layout(true);
    if (!fuseFill && !layout(false)) return;  // scratch too small: fail cleanly

    // ---- prep ----
    k_wa<<<(7168 + 255) / 256, 256, 0, stream>>>(lin_w, att_src, att_dst, was, wad);
    k_wt<<<(14 * 4096 + 255) / 256, 256, 0, stream>>>(lin_w, wt);
    k_wtin<<<32, 256, 0, stream>>>(Win_user, Win_tx, Win_merch, wtin);
    k_zero_u<<<(TN3w + 255) / 256, 256, 0, stream>>>(cnt3, TN3w);

    // ---- fuseA: hist || input projections (Bresenham) ----
    int Hb = (TE + 255) / 256;
    int Pt = (NT + 63) / 64, Pu = (NU + 63) / 64, Pm = (NM + 63) / 64;
    {
        PJ pt = {x_tx, wtin + 4096, bin_tx, A[1], NT};
        PJ pu = {x_user, wtin, bin_user, A[0], NU};
        PJ pm = {x_merch, wtin + 12288, bin_merch, A[2], NM};
        int T = Hb + Pt + Pu + Pm;
        k_fuseA<<<T, 256, 0, stream>>>(segs, TE, cnt3, rank, pt, pu, pm, Hb, T, Pt, Pu);
    }

    // ---- CSR mid chain (mkrp merged into scan1) ----
    int nb = (TN + 256) / 256;
    k_scan1m<<<nb, 256, 0, stream>>>(cnt3, TN, bsum, cnt, degp);
    k_scan2<<<1, 256, 0, stream>>>(bsum, nb);
    k_scan3<<<nb, 256, 0, stream>>>(cnt, TN, bsum, rp_all);
    if (!fuseFill)
        k_fill_all<<<(TE + 255) / 256, 256, 0, stream>>>(segs, TE, rp_all, degp, rank, col_all);

    const int bat_src[3]     = {1, 0, 2};
    const int bat_rels[3][3] = {{1, 3, 6}, {0, 4, -1}, {2, 5, -1}};
    const int bat_wad[3][2]  = {{0, 2}, {1, -1}, {3, -1}};

    // ================= layer 0 projections (all 7 relations) =================
    {
        int l = 0;
        PMX pmx[3];
        for (int b = 0; b < 3; b++) {
            int st = bat_src[b];
            int nrel = (bat_rels[b][2] >= 0) ? 3 : 2;
            P3 p;
            for (int jj = 0; jj < 3; jj++) {
                int r = bat_rels[b][jj] >= 0 ? bat_rels[b][jj] : bat_rels[b][0];
                int lr = l * 7 + r;
                p.wt[jj]  = wt + (size_t)lr * 8192;
                p.waS[jj] = (const float4*)(was + (size_t)lr * 256);
                p.hs[jj]  = hsArr[r];
                p.aS[jj]  = aS7[r];
            }
            int selfR = bat_rels[b][nrel - 1];
            p.wadL = (const float4*)(wad + (size_t)(l * 7 + selfR) * 256);
            p.aDL  = aD7[selfR];
            int wr0 = bat_wad[b][0], wr1 = bat_wad[b][1];
            p.wadA = (const float4*)(wad + (size_t)(l * 7 + wr0) * 256);
            p.aDA  = aD7[wr0];
            p.wadB = (wr1 >= 0) ? (const float4*)(wad + (size_t)(l * 7 + wr1) * 256) : nullptr;
            p.aDB  = (wr1 >= 0) ? aD7[wr1] : nullptr;
            pmx[b].x = A[st];
            pmx[b].p = p;
            pmx[b].N = N_of[st];
        }
        int b0 = (pmx[0].N + 63) / 64;
        int b1 = (pmx[1].N + 63) / 64;
        int b2 = (pmx[2].N + 63) / 64;
        if (fuseFill) {
            int Fb = (TE + 255) / 256;
            int T = Fb + b0 + b1 + b2;
            k_pmf3xF<<<T, 256, 0, stream>>>(pmx[0], pmx[1], pmx[2], b0, b0 + b1,
                                            segs, TE, rp_all, degp, rank, col_all, Fb, T);
        } else {
            k_pmf3x<<<b0 + b1 + b2, 256, 0, stream>>>(pmx[0], pmx[1], pmx[2], b0, b0 + b1);
        }
    }

    // ================= L0 t-group aggregation =================
    {
        FGA fgt0;
        fgt0.rp   = rp_all + type_base[1];
        fgt0.degp = degp + type_base[1];
        fgt0.col  = col_all;
        fgt0.aS0 = aS7[0]; fgt0.aS1 = aS7[2]; fgt0.aS2 = aS7[6];
        fgt0.aD0 = aD7[0]; fgt0.aD1 = aD7[2]; fgt0.aD2 = aD7[6];
        fgt0.h0 = hsArr[0]; fgt0.h1 = hsArr[2]; fgt0.h2 = hsArr[6];
        fgt0.cb = conv_bias; fgt0.b0 = 0; fgt0.b1 = 2; fgt0.b2 = 6;
        fgt0.out = A[1]; fgt0.Nd = NT;
        k_fagg1<<<(NT + 7) / 8, 256, 0, stream>>>(fgt0);
    }

    // ================= fuseB: L0 u/m aggregation || L1 t-src projection =================
    {
        FGA fu, fm;
        fu.rp   = rp_all + type_base[0];
        fu.degp = degp + type_base[0];
        fu.col  = col_all;
        fu.aS0 = aS7[1]; fu.aS1 = aS7[4]; fu.aS2 = aS7[1];
        fu.aD0 = aD7[1]; fu.aD1 = aD7[4]; fu.aD2 = aD7[1];
        fu.h0 = hsArr[1]; fu.h1 = hsArr[4]; fu.h2 = hsArr[1];
        fu.cb = conv_bias; fu.b0 = 1; fu.b1 = 4; fu.b2 = -1;
        fu.out = A[0]; fu.Nd = NU;
        fm.rp   = rp_all + type_base[2];
        fm.degp = degp + type_base[2];
        fm.col  = col_all;
        fm.aS0 = aS7[3]; fm.aS1 = aS7[5]; fm.aS2 = aS7[3];
        fm.aD0 = aD7[3]; fm.aD1 = aD7[5]; fm.aD2 = aD7[3];
        fm.h0 = hsArr[3]; fm.h1 = hsArr[5]; fm.h2 = hsArr[3];
        fm.cb = conv_bias; fm.b0 = 3; fm.b1 = 5; fm.b2 = -1;
        fm.out = A[2]; fm.Nd = NM;

        PMX pt;
        {
            P3 p = {};
            int lr = 7 + 6;
            p.wt[0]  = wt + (size_t)lr * 8192;
            p.waS[0] = (const float4*)(was + (size_t)lr * 256);
            p.hs[0]  = hsArr[6];
            p.aS[0]  = aS7[6];
            p.wadL = (const float4*)(wad + (size_t)lr * 256);
            p.aDL  = aD7[6];
            p.wadA = (const float4*)(wad + (size_t)(7 + 0) * 256);
            p.aDA  = aD7[0];
            p.wadB = (const float4*)(wad + (size_t)(7 + 2) * 256);
            p.aDB  = aD7[2];
            pt.x = A[1]; pt.p = p; pt.N = NT;
        }
        int ub = (NU + 7) / 8;
        int mb = (NM + 7) / 8;
        int Fb = ub + mb;
        int Pb = (NT + 63) / 64;
        int T = Fb + Pb;
        k_fuseB<<<T, 256, 0, stream>>>(fu, fm, ub, pt, Fb, T);
    }

    // ================= L1 u-src, m-src projections =================
    {
        PMX pu, pm;
        {
            P3 p = {};
            int lr = 7 + 0;
            p.wt[0]  = wt + (size_t)lr * 8192;
            p.waS[0] = (const float4*)(was + (size_t)lr * 256);
            p.hs[0]  = hsArr[0];
            p.aS[0]  = aS7[0];
            pu.x = A[0]; pu.p = p; pu.N = NU;
        }
        {
            P3 p = {};
            int lr = 7 + 2;
            p.wt[0]  = wt + (size_t)lr * 8192;
            p.waS[0] = (const float4*)(was + (size_t)lr * 256);
            p.hs[0]  = hsArr[2];
            p.aS[0]  = aS7[2];
            pm.x = A[2]; pm.p = p; pm.N = NM;
        }
        int b0 = (NU + 63) / 64;
        int b1 = (NM + 63) / 64;
        k_pmf1s<<<b0 + b1, 256, 0, stream>>>(pu, pm, b0);
    }

    // ================= L1 t-group aggregation =================
    {
        FGA a;
        a.rp   = rp_all + type_base[1];
        a.degp = degp + type_base[1];
        a.col  = col_all;
        a.aS0 = aS7[0]; a.aS1 = aS7[2]; a.aS2 = aS7[6];
        a.aD0 = aD7[0]; a.aD1 = aD7[2]; a.aD2 = aD7[6];
        a.h0 = hsArr[0]; a.h1 = hsArr[2]; a.h2 = hsArr[6];
        a.cb = conv_bias + (size_t)7 * 64; a.b0 = 0; a.b1 = 2; a.b2 = 6;
        a.out = A[1]; a.Nd = NT;
        k_fagg1<<<(NT + 7) / 8, 256, 0, stream>>>(a);
    }
    k_cls<<<NT / 8, 256, 0, stream>>>(A[1], cls_w1, cls_b1, cls_w2, cls_b2, (float*)d_out);
}